// Round 5
// baseline (764.743 us; speedup 1.0000x reference)
//
#include <hip/hip_runtime.h>

// BasicMotionEncoder (RAFT): B=8, H=96, W=128, CORR=324.
// Round 10: structural data-movement removal (conv cores byte-identical to R4).
//  - nchw2nhwc_bf16 DELETED: conv1 is now mfma_gemm_nchw, staging NCHW f32
//    directly to LDS [oct][px][8] bf16 (coalesced 4B loads, ds_write_b128,
//    bank-free read/write by construction). Removes a 196-MB pass.
//  - nhwc_bf16_2nchw DELETED: conv5 (mfma_conv3<...,true>) stores float4
//    directly to NCHW f32 out (acc[mf][nf][0..3] = 4 consecutive gx at fixed
//    gy,oc — no LDS transpose needed).
//  - 5 repacks + zero_halo3 fused into one prep kernel (corrT gone -> cat
//    halo can be zeroed up front). 15 launches -> 8.

typedef __bf16 bf16x8 __attribute__((ext_vector_type(8)));
typedef float f32x4 __attribute__((ext_vector_type(4)));

__device__ __forceinline__ unsigned short f2bf(float f) {
  __bf16 h = (__bf16)f;
  return __builtin_bit_cast(unsigned short, h);
}

__device__ __forceinline__ void gload_lds16(const unsigned short* g,
                                            unsigned short* l) {
  __builtin_amdgcn_global_load_lds(
      (const __attribute__((address_space(1))) unsigned int*)g,
      (__attribute__((address_space(3))) unsigned int*)l, 16, 0, 0);
}

// ---------------- prep: all weight repacks + halo zeroing, one launch --------
__global__ __launch_bounds__(256) void prep(
    const float* __restrict__ wc1, const float* __restrict__ wc2,
    const float* __restrict__ wf2, const float* __restrict__ wo,
    const float* __restrict__ wf1, unsigned short* __restrict__ p1,
    unsigned short* __restrict__ p2, unsigned short* __restrict__ p3,
    unsigned short* __restrict__ p4, unsigned short* __restrict__ pf1,
    unsigned short* __restrict__ hb0, unsigned short* __restrict__ hb1,
    unsigned short* __restrict__ hb2) {
  const int task = blockIdx.y;
  const int tid0 = blockIdx.x * 256 + threadIdx.x;
  if (task < 4) {
    // OIHW f32 -> [tap][icq][OCP][8] bf16
    const float* w;
    unsigned short* dst;
    int O, I, K2, ICQ, OCP;
    if (task == 0) { w = wc1; dst = p1; O = 256; I = 324; K2 = 1;  ICQ = 44; OCP = 256; }
    else if (task == 1) { w = wc2; dst = p2; O = 192; I = 256; K2 = 9; ICQ = 32; OCP = 192; }
    else if (task == 2) { w = wf2; dst = p3; O = 64;  I = 128; K2 = 9; ICQ = 16; OCP = 64; }
    else { w = wo; dst = p4; O = 126; I = 256; K2 = 9; ICQ = 32; OCP = 128; }
    int n = K2 * ICQ * OCP * 8;
    for (int s = tid0; s < n; s += gridDim.x * 256) {
      int j = s & 7;
      int r = s >> 3;
      int oc = r % OCP;
      r /= OCP;
      int icq = r % ICQ;
      int tap = r / ICQ;
      int ic = icq * 8 + j;
      float v = (oc < O && ic < I) ? w[((size_t)oc * I + ic) * K2 + tap] : 0.f;
      dst[s] = f2bf(v);
    }
  } else if (task == 4) {
    // wf1 [128][2][7][7] -> [kq=16][128][8], k = ic*49 + dy*7 + dx
    int s = tid0;
    if (s < 16384) {
      int j = s & 7;
      int oc = (s >> 3) & 127;
      int kq = s >> 10;
      int k = kq * 8 + j;
      float v = 0.f;
      if (k < 98) {
        int ic = k / 49;
        int tap = k - ic * 49;
        v = wf1[(oc * 2 + ic) * 49 + tap];
      }
      pf1[s] = f2bf(v);
    }
  } else {
    // zero the 1-px halo border
    unsigned short* buf = (task == 5) ? hb0 : (task == 6) ? hb1 : hb2;
    const int C = (task == 7) ? 128 : 256;
    const int cq = C >> 3;
    int n = 8 * 452 * cq;
    int i = tid0;
    if (i >= n) return;
    int c = i % cq;
    int t = i / cq;
    int bp = t % 452;
    int bb = t / 452;
    int y, x;
    if (bp < 130) { y = 0; x = bp; }
    else if (bp < 260) { y = 97; x = bp - 130; }
    else { int r = bp - 260; y = 1 + (r >> 1); x = (r & 1) ? 129 : 0; }
    *(uint4*)&buf[((size_t)(bb * 98 + y) * 130 + x) * C + c * 8] =
        make_uint4(0, 0, 0, 0);
  }
}

// ------------- im2col of flow: [8][2][96][128] f32 -> [NPX][128] bf16 --------
__global__ __launch_bounds__(256) void im2col_flow(const float* __restrict__ f,
                                                   unsigned short* __restrict__ o,
                                                   int H, int W) {
  int s = blockIdx.x * 256 + threadIdx.x;  // over NPX*16
  int kq = s & 15;
  int px = s >> 4;
  int HW = H * W;
  int b = px / HW;
  int r = px % HW;
  int y = r / W;
  int x = r % W;
  unsigned short pk[8];
#pragma unroll
  for (int j = 0; j < 8; ++j) {
    int k = kq * 8 + j;
    float v = 0.f;
    if (k < 98) {
      int ic = k / 49;
      int t = k - ic * 49;
      int dy = t / 7, dx = t - dy * 7;
      int yy = y + dy - 3, xx = x + dx - 3;
      if (yy >= 0 && yy < H && xx >= 0 && xx < W)
        v = f[((size_t)(b * 2 + ic) * H + yy) * W + xx];
    }
    pk[j] = f2bf(v);
  }
  *(uint4*)&o[(size_t)px * 128 + kq * 8] = *(uint4*)pk;
}

// =================== 1x1 MFMA GEMM (bf16 NHWC input, no barriers) ============
template <int CINP, int NF>
__global__ __launch_bounds__(256, 2) void mfma_gemm(
    const unsigned short* __restrict__ xin,  // [B*H*W][CINP]
    const unsigned short* __restrict__ wpk,  // [CINP/8][OCP][8]
    const float* __restrict__ bias, unsigned short* __restrict__ yout,
    int H, int W, int Cout, int OCP, int CT, int coff, int Wo, int oh) {
  __shared__ __align__(16) unsigned short smem[NF * 2048];
  const int tid = threadIdx.x;
  const int wave = tid >> 6, lane = tid & 63;
  const int l15 = lane & 15, lq = lane >> 4;
  const int tilesX = W >> 4;
  const int perB = (H >> 4) * tilesX;
  const int b = blockIdx.x / perB;
  const int r0 = blockIdx.x % perB;
  const int ty0 = (r0 / tilesX) << 4;
  const int tx0 = (r0 % tilesX) << 4;
  const int oc0 = blockIdx.y * (NF * 16);

  f32x4 acc[4][NF];
#pragma unroll
  for (int mf = 0; mf < 4; ++mf)
#pragma unroll
    for (int nf = 0; nf < NF; ++nf) acc[mf][nf] = (f32x4){0.f, 0.f, 0.f, 0.f};

  size_t rowA[4];
#pragma unroll
  for (int mf = 0; mf < 4; ++mf)
    rowA[mf] =
        ((size_t)(b * H + ty0 + wave * 4 + mf) * W + tx0 + l15) * CINP + lq * 8;
  const unsigned short* wB = wpk + ((size_t)lq * OCP + oc0 + l15) * 8;
  const int icbStr = 4 * OCP * 8;

  constexpr int NI = CINP / 32;
#pragma unroll 2
  for (int icb = 0; icb < NI; ++icb) {
    bf16x8 va[4], vb[NF];
#pragma unroll
    for (int mf = 0; mf < 4; ++mf)
      va[mf] = *(const bf16x8*)&xin[rowA[mf] + icb * 32];
#pragma unroll
    for (int nf = 0; nf < NF; ++nf)
      vb[nf] = *(const bf16x8*)&wB[icb * icbStr + nf * 128];
    __builtin_amdgcn_s_setprio(1);
#pragma unroll
    for (int mf = 0; mf < 4; ++mf)
#pragma unroll
      for (int nf = 0; nf < NF; ++nf)
        acc[mf][nf] = __builtin_amdgcn_mfma_f32_16x16x32_bf16(
            va[mf], vb[nf], acc[mf][nf], 0, 0, 0);
    __builtin_amdgcn_s_setprio(0);
  }

  float bsv[NF];
#pragma unroll
  for (int nf = 0; nf < NF; ++nf) {
    int oc = oc0 + nf * 16 + l15;
    bsv[nf] = (oc < Cout) ? bias[oc] : 0.f;
  }
  unsigned short* slice = smem + wave * (NF * 512);
  const int Ho = H + 2 * oh;
#pragma unroll
  for (int pass = 0; pass < 2; ++pass) {
#pragma unroll
    for (int mf = 0; mf < 4; ++mf)
#pragma unroll
      for (int h = 0; h < NF / 2; ++h) {
        const int nf = pass * (NF / 2) + h;
#pragma unroll
        for (int r = 0; r < 4; ++r)
          slice[(mf * 16 + lq * 4 + r) * (NF * 8) + h * 16 + l15] =
              f2bf(fmaxf(acc[mf][nf][r] + bsv[nf], 0.f));
      }
#pragma unroll
    for (int j = 0; j < NF; ++j) {
      int c = j * 64 + lane;
      int pxl = c / NF;
      int ocq = (c - pxl * NF) * 8;
      uint4 v = *(uint4*)&slice[pxl * (NF * 8) + ocq];
      int pxg = wave * 64 + pxl;
      int gy = ty0 + (pxg >> 4) + oh, gx = tx0 + (pxg & 15) + oh;
      *(uint4*)&yout[((size_t)(b * Ho + gy) * Wo + gx) * CT + coff + oc0 +
                     pass * (NF * 8) + ocq] = v;
    }
  }
}

// ====== 1x1 MFMA GEMM reading NCHW f32 (fused transpose in LDS staging) ======
// Staging per icb (32 ch): wave w loads ch w*8..w*8+7 (coalesced 4B, 64B runs),
// packs 8 bf16, ds_write_b128 to [oct=w][px][8]. Read: va = [lq][px][8] 16B.
template <int NF>
__global__ __launch_bounds__(256, 2) void mfma_gemm_nchw(
    const float* __restrict__ xin,           // [B][324][H][W] f32
    const unsigned short* __restrict__ wpk,  // [44][OCP][8]
    const float* __restrict__ bias, unsigned short* __restrict__ yout,
    int H, int W, int Cout, int OCP, int CT, int coff, int Wo, int oh) {
  constexpr int NI = 11;  // 352/32 (ch 324..351 zero-padded)
  __shared__ __align__(16) unsigned short smem[16384];  // 2 x [4][256][8]
  const int tid = threadIdx.x;
  const int wave = tid >> 6, lane = tid & 63;
  const int l15 = lane & 15, lq = lane >> 4;
  const int HW = H * W;
  const int tilesX = W >> 4;
  const int perB = (H >> 4) * tilesX;
  const int b = blockIdx.x / perB;
  const int r0 = blockIdx.x % perB;
  const int ty0 = (r0 / tilesX) << 4;
  const int tx0 = (r0 % tilesX) << 4;
  const int oc0 = blockIdx.y * (NF * 16);

  f32x4 acc[4][NF];
#pragma unroll
  for (int mf = 0; mf < 4; ++mf)
#pragma unroll
    for (int nf = 0; nf < NF; ++nf) acc[mf][nf] = (f32x4){0.f, 0.f, 0.f, 0.f};

  const unsigned short* wB = wpk + ((size_t)lq * OCP + oc0 + l15) * 8;
  const int icbStr = 4 * OCP * 8;
  // per-thread global staging base: row ty0+lq, col tx0+l15 of batch b
  const float* gsrc =
      xin + (size_t)b * 324 * HW + (size_t)(ty0 + lq) * W + tx0 + l15;

  float ld[32];
  // prologue: stage icb 0 into buf 0
#pragma unroll
  for (int j = 0; j < 8; ++j) {
    int ch = wave * 8 + j;
    const float* cp = gsrc + (size_t)ch * HW;
#pragma unroll
    for (int p = 0; p < 4; ++p) ld[j * 4 + p] = cp[p * 4 * W];
  }
#pragma unroll
  for (int p = 0; p < 4; ++p) {
    unsigned short pk[8];
#pragma unroll
    for (int j = 0; j < 8; ++j) pk[j] = f2bf(ld[j * 4 + p]);
    *(uint4*)&smem[(wave * 256 + lane + p * 64) * 8] = *(uint4*)pk;
  }

  for (int icb = 0; icb < NI; ++icb) {
    __syncthreads();  // buf[icb&1] visible; buf[other] free
    const int curOff = (icb & 1) * 8192;
    const bool have = (icb + 1 < NI);
    if (have) {  // issue next-icb global loads (latency hides under MFMAs)
#pragma unroll
      for (int j = 0; j < 8; ++j) {
        int ch = (icb + 1) * 32 + wave * 8 + j;
        const float* cp = gsrc + (size_t)ch * HW;
        bool ok = ch < 324;
#pragma unroll
        for (int p = 0; p < 4; ++p) ld[j * 4 + p] = ok ? cp[p * 4 * W] : 0.f;
      }
    }
    bf16x8 va[4], vb[NF];
    const unsigned short* wbi = wB + (size_t)icb * icbStr;
#pragma unroll
    for (int nf = 0; nf < NF; ++nf) vb[nf] = *(const bf16x8*)&wbi[nf * 128];
#pragma unroll
    for (int mf = 0; mf < 4; ++mf)
      va[mf] = *(const bf16x8*)
          &smem[curOff + (lq * 256 + (wave * 4 + mf) * 16 + l15) * 8];
    __builtin_amdgcn_s_setprio(1);
#pragma unroll
    for (int mf = 0; mf < 4; ++mf)
#pragma unroll
      for (int nf = 0; nf < NF; ++nf)
        acc[mf][nf] = __builtin_amdgcn_mfma_f32_16x16x32_bf16(
            va[mf], vb[nf], acc[mf][nf], 0, 0, 0);
    __builtin_amdgcn_s_setprio(0);
    if (have) {  // convert + LDS write into the other buffer
      const int nxtOff = curOff ^ 8192;
#pragma unroll
      for (int p = 0; p < 4; ++p) {
        unsigned short pk[8];
#pragma unroll
        for (int j = 0; j < 8; ++j) pk[j] = f2bf(ld[j * 4 + p]);
        *(uint4*)&smem[nxtOff + (wave * 256 + lane + p * 64) * 8] =
            *(uint4*)pk;
      }
    }
  }
  __syncthreads();

  // epilogue: identical to mfma_gemm (bf16 NHWC halo write)
  float bsv[NF];
#pragma unroll
  for (int nf = 0; nf < NF; ++nf) {
    int oc = oc0 + nf * 16 + l15;
    bsv[nf] = (oc < Cout) ? bias[oc] : 0.f;
  }
  unsigned short* slice = smem + wave * (NF * 512);
  const int Ho = H + 2 * oh;
#pragma unroll
  for (int pass = 0; pass < 2; ++pass) {
#pragma unroll
    for (int mf = 0; mf < 4; ++mf)
#pragma unroll
      for (int h = 0; h < NF / 2; ++h) {
        const int nf = pass * (NF / 2) + h;
#pragma unroll
        for (int r = 0; r < 4; ++r)
          slice[(mf * 16 + lq * 4 + r) * (NF * 8) + h * 16 + l15] =
              f2bf(fmaxf(acc[mf][nf][r] + bsv[nf], 0.f));
      }
#pragma unroll
    for (int j = 0; j < NF; ++j) {
      int c = j * 64 + lane;
      int pxl = c / NF;
      int ocq = (c - pxl * NF) * 8;
      uint4 v = *(uint4*)&slice[pxl * (NF * 8) + ocq];
      int pxg = wave * 64 + pxl;
      int gy = ty0 + (pxg >> 4) + oh, gx = tx0 + (pxg & 15) + oh;
      *(uint4*)&yout[((size_t)(b * Ho + gy) * Wo + gx) * CT + coff + oc0 +
                     pass * (NF * 8) + ocq] = v;
    }
  }
}

// =================== 3x3 MFMA conv (halo input, dbuf LDS A, global B) ========
// F32OUT=true: store float4 direct to NCHW f32 (acc[..][r] = 4 consecutive gx).
template <int CINP, int NF, bool F32OUT>
__global__ __launch_bounds__(256, 2) void mfma_conv3(
    const unsigned short* __restrict__ xin,  // [B][H+2][W+2][CINP] halo
    const unsigned short* __restrict__ wpk,  // [9][CINP/8][OCP][8]
    const float* __restrict__ bias, void* __restrict__ yout,
    int H, int W, int Cout, int OCP, int CT, int coff, int Wo, int oh) {
  const int Hp = H + 2, Wp = W + 2;
  constexpr int ICQS = CINP / 8;
  constexpr int NI = CINP / 32;
  __shared__ __align__(16) unsigned short smem[24576];  // 2 x 1536 chunks

  const int tid = threadIdx.x;
  const int wave = tid >> 6, lane = tid & 63;
  const int l15 = lane & 15, lq = lane >> 4;
  const int tilesX = W >> 4;
  const int perB = (H >> 4) * tilesX;
  const int b = blockIdx.x / perB;
  const int r0 = blockIdx.x % perB;
  const int ty0 = (r0 / tilesX) << 4;
  const int tx0 = (r0 % tilesX) << 4;
  const int oc0 = blockIdx.y * (NF * 16);

  f32x4 acc[4][NF];
#pragma unroll
  for (int mf = 0; mf < 4; ++mf)
#pragma unroll
    for (int nf = 0; nf < NF; ++nf) acc[mf][nf] = (f32x4){0.f, 0.f, 0.f, 0.f};

  const size_t rowbase = (size_t)(b * Hp + ty0) * Wp + tx0;
  const unsigned short* gp[6];
#pragma unroll
  for (int k = 0; k < 6; ++k) {
    int e = tid + k * 256;
    int q = e / 384;
    int r = e - q * 384;
    int rc = (r < 324) ? r : 323;  // pad lanes load a harmless valid chunk
    int py = rc / 18, px = rc - py * 18;
    gp[k] = xin + (rowbase + (size_t)py * Wp + px) * CINP + q * 8;
  }
  const unsigned short* wB = wpk + ((size_t)lq * OCP + oc0 + l15) * 8;
  const int icbStr = 4 * OCP * 8;
  const int tapStr = ICQS * OCP * 8;

#pragma unroll
  for (int k = 0; k < 6; ++k)
    gload_lds16(gp[k], smem + (tid + k * 256) * 8);

  for (int icb = 0; icb < NI; ++icb) {
    const int curOff = (icb & 1) * 12288;
    __syncthreads();
    if (icb + 1 < NI) {
      const int nxtOff = curOff ^ 12288;
#pragma unroll
      for (int k = 0; k < 6; ++k)
        gload_lds16(gp[k] + (icb + 1) * 32,
                    smem + nxtOff + (tid + k * 256) * 8);
    }
    const unsigned short* wbi = wB + icb * icbStr;
#pragma unroll
    for (int tap = 0; tap < 9; ++tap) {
      const int dy = tap / 3, dx = tap - dy * 3;
      bf16x8 vb[NF], va[4];
#pragma unroll
      for (int nf = 0; nf < NF; ++nf)
        vb[nf] = *(const bf16x8*)&wbi[tap * tapStr + nf * 128];
#pragma unroll
      for (int mf = 0; mf < 4; ++mf)
        va[mf] = *(const bf16x8*)
            &smem[curOff +
                  (lq * 384 + (wave * 4 + mf + dy) * 18 + l15 + dx) * 8];
      __builtin_amdgcn_s_setprio(1);
#pragma unroll
      for (int mf = 0; mf < 4; ++mf)
#pragma unroll
        for (int nf = 0; nf < NF; ++nf)
          acc[mf][nf] = __builtin_amdgcn_mfma_f32_16x16x32_bf16(
              va[mf], vb[nf], acc[mf][nf], 0, 0, 0);
      __builtin_amdgcn_s_setprio(0);
    }
  }
  __syncthreads();

  if constexpr (F32OUT) {
    // direct NCHW f32 store: thread holds (gy=ty0+wave*4+mf, gx=tx0+lq*4+r,
    // oc=oc0+nf*16+l15); r spans 4 consecutive gx -> one float4 per (mf,nf).
    float* op = (float*)yout;
#pragma unroll
    for (int nf = 0; nf < NF; ++nf) {
      int oc = oc0 + nf * 16 + l15;
      if (oc < Cout) {
        float bv = bias[oc];
#pragma unroll
        for (int mf = 0; mf < 4; ++mf) {
          float4 v;
          v.x = fmaxf(acc[mf][nf][0] + bv, 0.f);
          v.y = fmaxf(acc[mf][nf][1] + bv, 0.f);
          v.z = fmaxf(acc[mf][nf][2] + bv, 0.f);
          v.w = fmaxf(acc[mf][nf][3] + bv, 0.f);
          *(float4*)&op[((size_t)(b * CT + coff + oc) * H + ty0 + wave * 4 +
                         mf) *
                            W +
                        tx0 + lq * 4] = v;
        }
      }
    }
  } else {
    unsigned short* yo = (unsigned short*)yout;
    float bsv[NF];
#pragma unroll
    for (int nf = 0; nf < NF; ++nf) {
      int oc = oc0 + nf * 16 + l15;
      bsv[nf] = (oc < Cout) ? bias[oc] : 0.f;
    }
    unsigned short* slice = smem + wave * (NF * 512);
    const int Ho = H + 2 * oh;
#pragma unroll
    for (int pass = 0; pass < 2; ++pass) {
#pragma unroll
      for (int mf = 0; mf < 4; ++mf)
#pragma unroll
        for (int h = 0; h < NF / 2; ++h) {
          const int nf = pass * (NF / 2) + h;
#pragma unroll
          for (int r = 0; r < 4; ++r)
            slice[(mf * 16 + lq * 4 + r) * (NF * 8) + h * 16 + l15] =
                f2bf(fmaxf(acc[mf][nf][r] + bsv[nf], 0.f));
        }
#pragma unroll
      for (int j = 0; j < NF; ++j) {
        int c = j * 64 + lane;
        int pxl = c / NF;
        int ocq = (c - pxl * NF) * 8;
        uint4 v = *(uint4*)&slice[pxl * (NF * 8) + ocq];
        int pxg = wave * 64 + pxl;
        int gy = ty0 + (pxg >> 4) + oh, gx = tx0 + (pxg & 15) + oh;
        *(uint4*)&yo[((size_t)(b * Ho + gy) * Wo + gx) * CT + coff + oc0 +
                     pass * (NF * 8) + ocq] = v;
      }
    }
  }
}

__global__ __launch_bounds__(256) void copy_flow(const float* __restrict__ flow,
                                                 float* __restrict__ out, int B,
                                                 int HW) {
  int q = HW / 4;
  int n = B * 2 * q;
  int i = blockIdx.x * blockDim.x + threadIdx.x;
  if (i < n) {
    float4 v = ((const float4*)flow)[i];
    int p = i % q;
    int t = i / q;
    int c = t % 2;
    int bb = t / 2;
    ((float4*)out)[((bb * 128 + 126 + c) * HW) / 4 + p] = v;
  }
}

extern "C" void kernel_launch(void* const* d_in, const int* in_sizes, int n_in,
                              void* d_out, int out_size, void* d_ws,
                              size_t ws_size, hipStream_t stream) {
  const float* flow = (const float*)d_in[0];
  const float* corr = (const float*)d_in[1];
  const float* wc1 = (const float*)d_in[2];
  const float* bc1 = (const float*)d_in[3];
  const float* wc2 = (const float*)d_in[4];
  const float* bc2 = (const float*)d_in[5];
  const float* wf1 = (const float*)d_in[6];
  const float* bf1 = (const float*)d_in[7];
  const float* wf2 = (const float*)d_in[8];
  const float* bf2 = (const float*)d_in[9];
  const float* wo = (const float*)d_in[10];
  const float* bo = (const float*)d_in[11];
  float* out = (float*)d_out;

  const int B = 8, H = 96, W = 128;
  const int HW = H * W;               // 12288
  const size_t NPX = (size_t)B * HW;  // 98304

  char* ws = (char*)d_ws;
  // R0: cat [8][98][130][256] bf16 (corrT eliminated)
  unsigned short* cat = (unsigned short*)(ws + 0);
  // R1: buf1 [8][98][130][256]; then fcol [NPX][128]
  unsigned short* buf1 = (unsigned short*)(ws + 69206016);
  unsigned short* fcol = (unsigned short*)(ws + 69206016);
  // R2: flo1 [8][98][130][128]
  unsigned short* flo1 = (unsigned short*)(ws + 121389056);
  // weights
  unsigned short* p1 = (unsigned short*)(ws + 147480576);   // [1][44][256][8]
  unsigned short* p2 = (unsigned short*)(ws + 147660800);   // [9][32][192][8]
  unsigned short* p3 = (unsigned short*)(ws + 148545536);   // [9][16][64][8]
  unsigned short* p4 = (unsigned short*)(ws + 148692992);   // [9][32][128][8]
  unsigned short* pf1 = (unsigned short*)(ws + 149282816);  // [16][128][8]

  // prep: 4 repacks + wf1 repack + halo-zero of buf1/cat/flo1 (one launch)
  prep<<<dim3(512, 8), dim3(256), 0, stream>>>(wc1, wc2, wf2, wo, wf1, p1, p2,
                                               p3, p4, pf1, buf1, cat, flo1);
  // conv1: 1x1 324(352)->256, reads NCHW f32 corr directly -> buf1 halo
  mfma_gemm_nchw<8><<<dim3(384, 2), dim3(256), 0, stream>>>(
      corr, p1, bc1, buf1, H, W, 256, 256, 256, 0, 130, 1);
  // conv2: 3x3 256->192 (96 oc/block), buf1 -> cat ch 0..191
  mfma_conv3<256, 6, false><<<dim3(384, 2), dim3(256), 0, stream>>>(
      buf1, p2, bc2, (void*)cat, H, W, 192, 192, 256, 0, 130, 1);
  // im2col flow (buf1 dead; fcol aliases it)
  im2col_flow<<<dim3(NPX * 16 / 256), dim3(256), 0, stream>>>(flow, fcol, H, W);
  // convf1 as 1x1 GEMM: 128(k)->128, fcol -> flo1 (halo write)
  mfma_gemm<128, 8><<<dim3(384, 1), dim3(256), 0, stream>>>(
      fcol, pf1, bf1, flo1, H, W, 128, 128, 128, 0, 130, 1);
  // convf2: 3x3 128->64, flo1 -> cat ch 192..255
  mfma_conv3<128, 4, false><<<dim3(384, 1), dim3(256), 0, stream>>>(
      flo1, p3, bf2, (void*)cat, H, W, 64, 64, 256, 192, 130, 1);
  // conv5: 3x3 256->126, cat -> out NCHW f32 directly (ch 0..125)
  mfma_conv3<256, 8, true><<<dim3(384, 1), dim3(256), 0, stream>>>(
      cat, p4, bo, (void*)out, H, W, 126, 128, 128, 0, 128, 0);
  // flow -> out ch 126..127
  copy_flow<<<dim3(192), dim3(256), 0, stream>>>(flow, out, B, HW);
}

// Round 6
// 511.489 us; speedup vs baseline: 1.4951x; 1.4951x over previous
//
#include <hip/hip_runtime.h>

// BasicMotionEncoder (RAFT): B=8, H=96, W=128, CORR=324.
// Round 11 = R4 (best stable structure) + the two verified R10 wins, with the
// spilling mfma_gemm_nchw REVERTED:
//  - conv1 back to nchw2nhwc_bf16 + mfma_gemm<352,8> (R10's fused NCHW conv1
//    spilled: needed ~220 VGPR, got 128 -> 150MB/dispatch scratch traffic,
//    MfmaUtil 2%, 353us. Shelved.)
//  - conv5 keeps F32OUT direct NCHW f32 store (nhwc_bf16_2nchw deleted).
//  - 5 weight repacks fused into one prep_w launch. zero_halo3 stays separate
//    (must run after conv1: corrT aliases cat).

typedef __bf16 bf16x8 __attribute__((ext_vector_type(8)));
typedef float f32x4 __attribute__((ext_vector_type(4)));

__device__ __forceinline__ unsigned short f2bf(float f) {
  __bf16 h = (__bf16)f;
  return __builtin_bit_cast(unsigned short, h);
}
__device__ __forceinline__ float bf2f(unsigned short u) {
  __bf16 h = __builtin_bit_cast(__bf16, u);
  return (float)h;
}

__device__ __forceinline__ void gload_lds16(const unsigned short* g,
                                            unsigned short* l) {
  __builtin_amdgcn_global_load_lds(
      (const __attribute__((address_space(1))) unsigned int*)g,
      (__attribute__((address_space(3))) unsigned int*)l, 16, 0, 0);
}

// ---------------- prep_w: all 5 weight repacks in one launch -----------------
__global__ __launch_bounds__(256) void prep_w(
    const float* __restrict__ wc1, const float* __restrict__ wc2,
    const float* __restrict__ wf2, const float* __restrict__ wo,
    const float* __restrict__ wf1, unsigned short* __restrict__ p1,
    unsigned short* __restrict__ p2, unsigned short* __restrict__ p3,
    unsigned short* __restrict__ p4, unsigned short* __restrict__ pf1) {
  const int task = blockIdx.y;
  const int tid0 = blockIdx.x * 256 + threadIdx.x;
  if (task < 4) {
    // OIHW f32 -> [tap][icq][OCP][8] bf16
    const float* w;
    unsigned short* dst;
    int O, I, K2, ICQ, OCP;
    if (task == 0) { w = wc1; dst = p1; O = 256; I = 324; K2 = 1;  ICQ = 44; OCP = 256; }
    else if (task == 1) { w = wc2; dst = p2; O = 192; I = 256; K2 = 9; ICQ = 32; OCP = 192; }
    else if (task == 2) { w = wf2; dst = p3; O = 64;  I = 128; K2 = 9; ICQ = 16; OCP = 64; }
    else { w = wo; dst = p4; O = 126; I = 256; K2 = 9; ICQ = 32; OCP = 128; }
    int n = K2 * ICQ * OCP * 8;
    for (int s = tid0; s < n; s += gridDim.x * 256) {
      int j = s & 7;
      int r = s >> 3;
      int oc = r % OCP;
      r /= OCP;
      int icq = r % ICQ;
      int tap = r / ICQ;
      int ic = icq * 8 + j;
      float v = (oc < O && ic < I) ? w[((size_t)oc * I + ic) * K2 + tap] : 0.f;
      dst[s] = f2bf(v);
    }
  } else {
    // wf1 [128][2][7][7] -> [kq=16][128][8], k = ic*49 + dy*7 + dx
    int s = tid0;
    if (s < 16384) {
      int j = s & 7;
      int oc = (s >> 3) & 127;
      int kq = s >> 10;
      int k = kq * 8 + j;
      float v = 0.f;
      if (k < 98) {
        int ic = k / 49;
        int tap = k - ic * 49;
        v = wf1[(oc * 2 + ic) * 49 + tap];
      }
      pf1[s] = f2bf(v);
    }
  }
}

// ------------- NCHW f32 -> NHWC bf16 (zero-padded channels) ------------------
__global__ __launch_bounds__(256) void nchw2nhwc_bf16(
    const float* __restrict__ in, unsigned short* __restrict__ outp, int C,
    int CP, int HW) {
  __shared__ float sls[64][65];
  int p0 = blockIdx.x * 64;
  int c0 = blockIdx.y * 64;
  int b = p0 / HW, hw0 = p0 % HW;
  int tid = threadIdx.x;
  for (int e = tid; e < 4096; e += 256) {
    int ch = e >> 6, px = e & 63;
    float v = 0.f;
    if (c0 + ch < C) v = in[(size_t)(b * C + c0 + ch) * HW + hw0 + px];
    sls[px][ch] = v;
  }
  __syncthreads();
  for (int e = tid; e < 512; e += 256) {
    int px = e >> 3, cc = e & 7;
    if (c0 + cc * 8 < CP) {
      unsigned short pk[8];
#pragma unroll
      for (int j = 0; j < 8; ++j) pk[j] = f2bf(sls[px][cc * 8 + j]);
      *(uint4*)&outp[(size_t)(p0 + px) * CP + c0 + cc * 8] = *(uint4*)pk;
    }
  }
}

// ------------- zero the 1-px halo border of the 3 padded buffers -------------
__global__ __launch_bounds__(256) void zero_halo3(unsigned short* b0,
                                                  unsigned short* b1,
                                                  unsigned short* b2) {
  unsigned short* buf = (blockIdx.y == 0) ? b0 : (blockIdx.y == 1) ? b1 : b2;
  const int C = (blockIdx.y == 2) ? 128 : 256;
  const int cq = C >> 3;
  int n = 8 * 452 * cq;
  int i = blockIdx.x * 256 + threadIdx.x;
  if (i >= n) return;
  int c = i % cq;
  int t = i / cq;
  int bp = t % 452;
  int bb = t / 452;
  int y, x;
  if (bp < 130) { y = 0; x = bp; }
  else if (bp < 260) { y = 97; x = bp - 130; }
  else { int r = bp - 260; y = 1 + (r >> 1); x = (r & 1) ? 129 : 0; }
  *(uint4*)&buf[((size_t)(bb * 98 + y) * 130 + x) * C + c * 8] =
      make_uint4(0, 0, 0, 0);
}

// ------------- im2col of flow: [8][2][96][128] f32 -> [NPX][128] bf16 --------
__global__ __launch_bounds__(256) void im2col_flow(const float* __restrict__ f,
                                                   unsigned short* __restrict__ o,
                                                   int H, int W) {
  int s = blockIdx.x * 256 + threadIdx.x;  // over NPX*16
  int kq = s & 15;
  int px = s >> 4;
  int HW = H * W;
  int b = px / HW;
  int r = px % HW;
  int y = r / W;
  int x = r % W;
  unsigned short pk[8];
#pragma unroll
  for (int j = 0; j < 8; ++j) {
    int k = kq * 8 + j;
    float v = 0.f;
    if (k < 98) {
      int ic = k / 49;
      int t = k - ic * 49;
      int dy = t / 7, dx = t - dy * 7;
      int yy = y + dy - 3, xx = x + dx - 3;
      if (yy >= 0 && yy < H && xx >= 0 && xx < W)
        v = f[((size_t)(b * 2 + ic) * H + yy) * W + xx];
    }
    pk[j] = f2bf(v);
  }
  *(uint4*)&o[(size_t)px * 128 + kq * 8] = *(uint4*)pk;
}

// =================== 1x1 MFMA GEMM (no LDS staging, no barriers) =============
// Block: 256 px x NF*16 oc; 4 waves x (64px x NF*16oc).
template <int CINP, int NF>
__global__ __launch_bounds__(256, 2) void mfma_gemm(
    const unsigned short* __restrict__ xin,  // [B*H*W][CINP]
    const unsigned short* __restrict__ wpk,  // [CINP/8][OCP][8]
    const float* __restrict__ bias, unsigned short* __restrict__ yout,
    int H, int W, int Cout, int OCP, int CT, int coff, int Wo, int oh) {
  __shared__ __align__(16) unsigned short smem[NF * 2048];
  const int tid = threadIdx.x;
  const int wave = tid >> 6, lane = tid & 63;
  const int l15 = lane & 15, lq = lane >> 4;
  const int tilesX = W >> 4;
  const int perB = (H >> 4) * tilesX;
  const int b = blockIdx.x / perB;
  const int r0 = blockIdx.x % perB;
  const int ty0 = (r0 / tilesX) << 4;
  const int tx0 = (r0 % tilesX) << 4;
  const int oc0 = blockIdx.y * (NF * 16);

  f32x4 acc[4][NF];
#pragma unroll
  for (int mf = 0; mf < 4; ++mf)
#pragma unroll
    for (int nf = 0; nf < NF; ++nf) acc[mf][nf] = (f32x4){0.f, 0.f, 0.f, 0.f};

  size_t rowA[4];
#pragma unroll
  for (int mf = 0; mf < 4; ++mf)
    rowA[mf] =
        ((size_t)(b * H + ty0 + wave * 4 + mf) * W + tx0 + l15) * CINP + lq * 8;
  const unsigned short* wB = wpk + ((size_t)lq * OCP + oc0 + l15) * 8;
  const int icbStr = 4 * OCP * 8;

  constexpr int NI = CINP / 32;
#pragma unroll 2
  for (int icb = 0; icb < NI; ++icb) {
    bf16x8 va[4], vb[NF];
#pragma unroll
    for (int mf = 0; mf < 4; ++mf)
      va[mf] = *(const bf16x8*)&xin[rowA[mf] + icb * 32];
#pragma unroll
    for (int nf = 0; nf < NF; ++nf)
      vb[nf] = *(const bf16x8*)&wB[icb * icbStr + nf * 128];
    __builtin_amdgcn_s_setprio(1);
#pragma unroll
    for (int mf = 0; mf < 4; ++mf)
#pragma unroll
      for (int nf = 0; nf < NF; ++nf)
        acc[mf][nf] = __builtin_amdgcn_mfma_f32_16x16x32_bf16(
            va[mf], vb[nf], acc[mf][nf], 0, 0, 0);
    __builtin_amdgcn_s_setprio(0);
  }

  // two-pass epilogue: bias+relu, per-wave LDS transpose, 16B stores
  float bsv[NF];
#pragma unroll
  for (int nf = 0; nf < NF; ++nf) {
    int oc = oc0 + nf * 16 + l15;
    bsv[nf] = (oc < Cout) ? bias[oc] : 0.f;
  }
  unsigned short* slice = smem + wave * (NF * 512);
  const int Ho = H + 2 * oh;
#pragma unroll
  for (int pass = 0; pass < 2; ++pass) {
#pragma unroll
    for (int mf = 0; mf < 4; ++mf)
#pragma unroll
      for (int h = 0; h < NF / 2; ++h) {
        const int nf = pass * (NF / 2) + h;
#pragma unroll
        for (int r = 0; r < 4; ++r)
          slice[(mf * 16 + lq * 4 + r) * (NF * 8) + h * 16 + l15] =
              f2bf(fmaxf(acc[mf][nf][r] + bsv[nf], 0.f));
      }
#pragma unroll
    for (int j = 0; j < NF; ++j) {
      int c = j * 64 + lane;
      int pxl = c / NF;
      int ocq = (c - pxl * NF) * 8;
      uint4 v = *(uint4*)&slice[pxl * (NF * 8) + ocq];
      int pxg = wave * 64 + pxl;
      int gy = ty0 + (pxg >> 4) + oh, gx = tx0 + (pxg & 15) + oh;
      *(uint4*)&yout[((size_t)(b * Ho + gy) * Wo + gx) * CT + coff + oc0 +
                     pass * (NF * 8) + ocq] = v;
    }
  }
}

// =================== 3x3 MFMA conv (halo input, dbuf LDS A, global B) ========
// F32OUT=true: store float4 direct to NCHW f32 (acc[..][r] = 4 consecutive gx).
template <int CINP, int NF, bool F32OUT>
__global__ __launch_bounds__(256, 2) void mfma_conv3(
    const unsigned short* __restrict__ xin,  // [B][H+2][W+2][CINP] halo
    const unsigned short* __restrict__ wpk,  // [9][CINP/8][OCP][8]
    const float* __restrict__ bias, void* __restrict__ yout,
    int H, int W, int Cout, int OCP, int CT, int coff, int Wo, int oh) {
  const int Hp = H + 2, Wp = W + 2;
  constexpr int ICQS = CINP / 8;
  constexpr int NI = CINP / 32;
  __shared__ __align__(16) unsigned short smem[24576];  // 2 x 1536 chunks

  const int tid = threadIdx.x;
  const int wave = tid >> 6, lane = tid & 63;
  const int l15 = lane & 15, lq = lane >> 4;
  const int tilesX = W >> 4;
  const int perB = (H >> 4) * tilesX;
  const int b = blockIdx.x / perB;
  const int r0 = blockIdx.x % perB;
  const int ty0 = (r0 / tilesX) << 4;
  const int tx0 = (r0 % tilesX) << 4;
  const int oc0 = blockIdx.y * (NF * 16);

  f32x4 acc[4][NF];
#pragma unroll
  for (int mf = 0; mf < 4; ++mf)
#pragma unroll
    for (int nf = 0; nf < NF; ++nf) acc[mf][nf] = (f32x4){0.f, 0.f, 0.f, 0.f};

  const size_t rowbase = (size_t)(b * Hp + ty0) * Wp + tx0;
  const unsigned short* gp[6];
#pragma unroll
  for (int k = 0; k < 6; ++k) {
    int e = tid + k * 256;
    int q = e / 384;
    int r = e - q * 384;
    int rc = (r < 324) ? r : 323;  // pad lanes load a harmless valid chunk
    int py = rc / 18, px = rc - py * 18;
    gp[k] = xin + (rowbase + (size_t)py * Wp + px) * CINP + q * 8;
  }
  const unsigned short* wB = wpk + ((size_t)lq * OCP + oc0 + l15) * 8;
  const int icbStr = 4 * OCP * 8;
  const int tapStr = ICQS * OCP * 8;

#pragma unroll
  for (int k = 0; k < 6; ++k)
    gload_lds16(gp[k], smem + (tid + k * 256) * 8);

  for (int icb = 0; icb < NI; ++icb) {
    const int curOff = (icb & 1) * 12288;
    __syncthreads();
    if (icb + 1 < NI) {
      const int nxtOff = curOff ^ 12288;
#pragma unroll
      for (int k = 0; k < 6; ++k)
        gload_lds16(gp[k] + (icb + 1) * 32,
                    smem + nxtOff + (tid + k * 256) * 8);
    }
    const unsigned short* wbi = wB + icb * icbStr;
#pragma unroll
    for (int tap = 0; tap < 9; ++tap) {
      const int dy = tap / 3, dx = tap - dy * 3;
      bf16x8 vb[NF], va[4];
#pragma unroll
      for (int nf = 0; nf < NF; ++nf)
        vb[nf] = *(const bf16x8*)&wbi[tap * tapStr + nf * 128];
#pragma unroll
      for (int mf = 0; mf < 4; ++mf)
        va[mf] = *(const bf16x8*)
            &smem[curOff +
                  (lq * 384 + (wave * 4 + mf + dy) * 18 + l15 + dx) * 8];
      __builtin_amdgcn_s_setprio(1);
#pragma unroll
      for (int mf = 0; mf < 4; ++mf)
#pragma unroll
        for (int nf = 0; nf < NF; ++nf)
          acc[mf][nf] = __builtin_amdgcn_mfma_f32_16x16x32_bf16(
              va[mf], vb[nf], acc[mf][nf], 0, 0, 0);
      __builtin_amdgcn_s_setprio(0);
    }
  }
  __syncthreads();

  if constexpr (F32OUT) {
    // direct NCHW f32 store: thread holds (gy=ty0+wave*4+mf, gx=tx0+lq*4+r,
    // oc=oc0+nf*16+l15); r spans 4 consecutive gx -> one float4 per (mf,nf).
    float* op = (float*)yout;
#pragma unroll
    for (int nf = 0; nf < NF; ++nf) {
      int oc = oc0 + nf * 16 + l15;
      if (oc < Cout) {
        float bv = bias[oc];
#pragma unroll
        for (int mf = 0; mf < 4; ++mf) {
          float4 v;
          v.x = fmaxf(acc[mf][nf][0] + bv, 0.f);
          v.y = fmaxf(acc[mf][nf][1] + bv, 0.f);
          v.z = fmaxf(acc[mf][nf][2] + bv, 0.f);
          v.w = fmaxf(acc[mf][nf][3] + bv, 0.f);
          *(float4*)&op[((size_t)(b * CT + coff + oc) * H + ty0 + wave * 4 +
                         mf) *
                            W +
                        tx0 + lq * 4] = v;
        }
      }
    }
  } else {
    unsigned short* yo = (unsigned short*)yout;
    float bsv[NF];
#pragma unroll
    for (int nf = 0; nf < NF; ++nf) {
      int oc = oc0 + nf * 16 + l15;
      bsv[nf] = (oc < Cout) ? bias[oc] : 0.f;
    }
    unsigned short* slice = smem + wave * (NF * 512);
    const int Ho = H + 2 * oh;
#pragma unroll
    for (int pass = 0; pass < 2; ++pass) {
#pragma unroll
      for (int mf = 0; mf < 4; ++mf)
#pragma unroll
        for (int h = 0; h < NF / 2; ++h) {
          const int nf = pass * (NF / 2) + h;
#pragma unroll
          for (int r = 0; r < 4; ++r)
            slice[(mf * 16 + lq * 4 + r) * (NF * 8) + h * 16 + l15] =
                f2bf(fmaxf(acc[mf][nf][r] + bsv[nf], 0.f));
        }
#pragma unroll
      for (int j = 0; j < NF; ++j) {
        int c = j * 64 + lane;
        int pxl = c / NF;
        int ocq = (c - pxl * NF) * 8;
        uint4 v = *(uint4*)&slice[pxl * (NF * 8) + ocq];
        int pxg = wave * 64 + pxl;
        int gy = ty0 + (pxg >> 4) + oh, gx = tx0 + (pxg & 15) + oh;
        *(uint4*)&yo[((size_t)(b * Ho + gy) * Wo + gx) * CT + coff + oc0 +
                     pass * (NF * 8) + ocq] = v;
      }
    }
  }
}

__global__ __launch_bounds__(256) void copy_flow(const float* __restrict__ flow,
                                                 float* __restrict__ out, int B,
                                                 int HW) {
  int q = HW / 4;
  int n = B * 2 * q;
  int i = blockIdx.x * blockDim.x + threadIdx.x;
  if (i < n) {
    float4 v = ((const float4*)flow)[i];
    int p = i % q;
    int t = i / q;
    int c = t % 2;
    int bb = t / 2;
    ((float4*)out)[((bb * 128 + 126 + c) * HW) / 4 + p] = v;
  }
}

extern "C" void kernel_launch(void* const* d_in, const int* in_sizes, int n_in,
                              void* d_out, int out_size, void* d_ws,
                              size_t ws_size, hipStream_t stream) {
  const float* flow = (const float*)d_in[0];
  const float* corr = (const float*)d_in[1];
  const float* wc1 = (const float*)d_in[2];
  const float* bc1 = (const float*)d_in[3];
  const float* wc2 = (const float*)d_in[4];
  const float* bc2 = (const float*)d_in[5];
  const float* wf1 = (const float*)d_in[6];
  const float* bf1 = (const float*)d_in[7];
  const float* wf2 = (const float*)d_in[8];
  const float* bf2 = (const float*)d_in[9];
  const float* wo = (const float*)d_in[10];
  const float* bo = (const float*)d_in[11];
  float* out = (float*)d_out;

  const int B = 8, H = 96, W = 128;
  const int HW = H * W;               // 12288
  const size_t NPX = (size_t)B * HW;  // 98304

  char* ws = (char*)d_ws;
  // R0: corrT [NPX][352] bf16; then cat [8][98][130][256] bf16
  unsigned short* corrT = (unsigned short*)(ws + 0);
  unsigned short* cat = (unsigned short*)(ws + 0);
  // R1: buf1 [8][98][130][256]; then fcol [NPX][128]
  unsigned short* buf1 = (unsigned short*)(ws + 69206016);
  unsigned short* fcol = (unsigned short*)(ws + 69206016);
  // R2: flo1 [8][98][130][128]
  unsigned short* flo1 = (unsigned short*)(ws + 121389056);
  // weights
  unsigned short* p1 = (unsigned short*)(ws + 147480576);   // [1][44][256][8]
  unsigned short* p2 = (unsigned short*)(ws + 147660800);   // [9][32][192][8]
  unsigned short* p3 = (unsigned short*)(ws + 148545536);   // [9][16][64][8]
  unsigned short* p4 = (unsigned short*)(ws + 148692992);   // [9][32][128][8]
  unsigned short* pf1 = (unsigned short*)(ws + 149282816);  // [16][128][8]

  // all weight repacks in one launch
  prep_w<<<dim3(512, 5), dim3(256), 0, stream>>>(wc1, wc2, wf2, wo, wf1, p1,
                                                 p2, p3, p4, pf1);
  // corr NCHW f32 -> dense NHWC bf16 (ch padded 324->352)
  nchw2nhwc_bf16<<<dim3(NPX / 64, 6), dim3(256), 0, stream>>>(corr, corrT, 324,
                                                              352, HW);
  // conv1: 1x1 352->256 (128 oc/block), corrT -> buf1 (halo write)
  mfma_gemm<352, 8><<<dim3(384, 2), dim3(256), 0, stream>>>(
      corrT, p1, bc1, buf1, H, W, 256, 256, 256, 0, 130, 1);
  // zero halos of buf1, cat, flo1 (corrT dead now; cat aliases it)
  zero_halo3<<<dim3(512, 3), dim3(256), 0, stream>>>(buf1, cat, flo1);
  // conv2: 3x3 256->192 (96 oc/block), buf1 -> cat ch 0..191
  mfma_conv3<256, 6, false><<<dim3(384, 2), dim3(256), 0, stream>>>(
      buf1, p2, bc2, (void*)cat, H, W, 192, 192, 256, 0, 130, 1);
  // im2col flow (buf1 dead; fcol aliases it)
  im2col_flow<<<dim3(NPX * 16 / 256), dim3(256), 0, stream>>>(flow, fcol, H, W);
  // convf1 as 1x1 GEMM: 128(k)->128, fcol -> flo1 (halo write)
  mfma_gemm<128, 8><<<dim3(384, 1), dim3(256), 0, stream>>>(
      fcol, pf1, bf1, flo1, H, W, 128, 128, 128, 0, 130, 1);
  // convf2: 3x3 128->64, flo1 -> cat ch 192..255
  mfma_conv3<128, 4, false><<<dim3(384, 1), dim3(256), 0, stream>>>(
      flo1, p3, bf2, (void*)cat, H, W, 64, 64, 256, 192, 130, 1);
  // conv5: 3x3 256->126, cat -> out NCHW f32 directly (ch 0..125)
  mfma_conv3<256, 8, true><<<dim3(384, 1), dim3(256), 0, stream>>>(
      cat, p4, bo, (void*)out, H, W, 126, 128, 128, 0, 128, 0);
  // flow -> out ch 126..127
  copy_flow<<<dim3(192), dim3(256), 0, stream>>>(flow, out, B, HW);
}

// Round 7
// 499.949 us; speedup vs baseline: 1.5296x; 1.0231x over previous
//
#include <hip/hip_runtime.h>

// BasicMotionEncoder (RAFT): B=8, H=96, W=128, CORR=324.
// Round 12 = R11 (511.5 us best) + vb register-prefetch pipeline in mfma_conv3:
//  - vmcnt is FIFO (oldest-first): tap0's weight-load wait was force-draining
//    the 6 global_load_lds A-stage ops issued before it (~300-900 cyc/icb),
//    and each tap's vb loads had only ~120 cyc of cover vs ~200+ cyc L2 lat.
//  - Fix: prime PFD taps of vb BEFORE issuing next-icb staging, prefetch
//    tap+PFD during each tap's MFMAs. PFD=2 for NF<=6 (~230 regs), PFD=1 for
//    NF=8 (~238 regs); all indices compile-time under the full unroll.
//  - Everything else byte-identical to R11.

typedef __bf16 bf16x8 __attribute__((ext_vector_type(8)));
typedef float f32x4 __attribute__((ext_vector_type(4)));

__device__ __forceinline__ unsigned short f2bf(float f) {
  __bf16 h = (__bf16)f;
  return __builtin_bit_cast(unsigned short, h);
}
__device__ __forceinline__ float bf2f(unsigned short u) {
  __bf16 h = __builtin_bit_cast(__bf16, u);
  return (float)h;
}

__device__ __forceinline__ void gload_lds16(const unsigned short* g,
                                            unsigned short* l) {
  __builtin_amdgcn_global_load_lds(
      (const __attribute__((address_space(1))) unsigned int*)g,
      (__attribute__((address_space(3))) unsigned int*)l, 16, 0, 0);
}

// ---------------- prep_w: all 5 weight repacks in one launch -----------------
__global__ __launch_bounds__(256) void prep_w(
    const float* __restrict__ wc1, const float* __restrict__ wc2,
    const float* __restrict__ wf2, const float* __restrict__ wo,
    const float* __restrict__ wf1, unsigned short* __restrict__ p1,
    unsigned short* __restrict__ p2, unsigned short* __restrict__ p3,
    unsigned short* __restrict__ p4, unsigned short* __restrict__ pf1) {
  const int task = blockIdx.y;
  const int tid0 = blockIdx.x * 256 + threadIdx.x;
  if (task < 4) {
    // OIHW f32 -> [tap][icq][OCP][8] bf16
    const float* w;
    unsigned short* dst;
    int O, I, K2, ICQ, OCP;
    if (task == 0) { w = wc1; dst = p1; O = 256; I = 324; K2 = 1;  ICQ = 44; OCP = 256; }
    else if (task == 1) { w = wc2; dst = p2; O = 192; I = 256; K2 = 9; ICQ = 32; OCP = 192; }
    else if (task == 2) { w = wf2; dst = p3; O = 64;  I = 128; K2 = 9; ICQ = 16; OCP = 64; }
    else { w = wo; dst = p4; O = 126; I = 256; K2 = 9; ICQ = 32; OCP = 128; }
    int n = K2 * ICQ * OCP * 8;
    for (int s = tid0; s < n; s += gridDim.x * 256) {
      int j = s & 7;
      int r = s >> 3;
      int oc = r % OCP;
      r /= OCP;
      int icq = r % ICQ;
      int tap = r / ICQ;
      int ic = icq * 8 + j;
      float v = (oc < O && ic < I) ? w[((size_t)oc * I + ic) * K2 + tap] : 0.f;
      dst[s] = f2bf(v);
    }
  } else {
    // wf1 [128][2][7][7] -> [kq=16][128][8], k = ic*49 + dy*7 + dx
    int s = tid0;
    if (s < 16384) {
      int j = s & 7;
      int oc = (s >> 3) & 127;
      int kq = s >> 10;
      int k = kq * 8 + j;
      float v = 0.f;
      if (k < 98) {
        int ic = k / 49;
        int tap = k - ic * 49;
        v = wf1[(oc * 2 + ic) * 49 + tap];
      }
      pf1[s] = f2bf(v);
    }
  }
}

// ------------- NCHW f32 -> NHWC bf16 (zero-padded channels) ------------------
__global__ __launch_bounds__(256) void nchw2nhwc_bf16(
    const float* __restrict__ in, unsigned short* __restrict__ outp, int C,
    int CP, int HW) {
  __shared__ float sls[64][65];
  int p0 = blockIdx.x * 64;
  int c0 = blockIdx.y * 64;
  int b = p0 / HW, hw0 = p0 % HW;
  int tid = threadIdx.x;
  for (int e = tid; e < 4096; e += 256) {
    int ch = e >> 6, px = e & 63;
    float v = 0.f;
    if (c0 + ch < C) v = in[(size_t)(b * C + c0 + ch) * HW + hw0 + px];
    sls[px][ch] = v;
  }
  __syncthreads();
  for (int e = tid; e < 512; e += 256) {
    int px = e >> 3, cc = e & 7;
    if (c0 + cc * 8 < CP) {
      unsigned short pk[8];
#pragma unroll
      for (int j = 0; j < 8; ++j) pk[j] = f2bf(sls[px][cc * 8 + j]);
      *(uint4*)&outp[(size_t)(p0 + px) * CP + c0 + cc * 8] = *(uint4*)pk;
    }
  }
}

// ------------- zero the 1-px halo border of the 3 padded buffers -------------
__global__ __launch_bounds__(256) void zero_halo3(unsigned short* b0,
                                                  unsigned short* b1,
                                                  unsigned short* b2) {
  unsigned short* buf = (blockIdx.y == 0) ? b0 : (blockIdx.y == 1) ? b1 : b2;
  const int C = (blockIdx.y == 2) ? 128 : 256;
  const int cq = C >> 3;
  int n = 8 * 452 * cq;
  int i = blockIdx.x * 256 + threadIdx.x;
  if (i >= n) return;
  int c = i % cq;
  int t = i / cq;
  int bp = t % 452;
  int bb = t / 452;
  int y, x;
  if (bp < 130) { y = 0; x = bp; }
  else if (bp < 260) { y = 97; x = bp - 130; }
  else { int r = bp - 260; y = 1 + (r >> 1); x = (r & 1) ? 129 : 0; }
  *(uint4*)&buf[((size_t)(bb * 98 + y) * 130 + x) * C + c * 8] =
      make_uint4(0, 0, 0, 0);
}

// ------------- im2col of flow: [8][2][96][128] f32 -> [NPX][128] bf16 --------
__global__ __launch_bounds__(256) void im2col_flow(const float* __restrict__ f,
                                                   unsigned short* __restrict__ o,
                                                   int H, int W) {
  int s = blockIdx.x * 256 + threadIdx.x;  // over NPX*16
  int kq = s & 15;
  int px = s >> 4;
  int HW = H * W;
  int b = px / HW;
  int r = px % HW;
  int y = r / W;
  int x = r % W;
  unsigned short pk[8];
#pragma unroll
  for (int j = 0; j < 8; ++j) {
    int k = kq * 8 + j;
    float v = 0.f;
    if (k < 98) {
      int ic = k / 49;
      int t = k - ic * 49;
      int dy = t / 7, dx = t - dy * 7;
      int yy = y + dy - 3, xx = x + dx - 3;
      if (yy >= 0 && yy < H && xx >= 0 && xx < W)
        v = f[((size_t)(b * 2 + ic) * H + yy) * W + xx];
    }
    pk[j] = f2bf(v);
  }
  *(uint4*)&o[(size_t)px * 128 + kq * 8] = *(uint4*)pk;
}

// =================== 1x1 MFMA GEMM (no LDS staging, no barriers) =============
// Block: 256 px x NF*16 oc; 4 waves x (64px x NF*16oc).
template <int CINP, int NF>
__global__ __launch_bounds__(256, 2) void mfma_gemm(
    const unsigned short* __restrict__ xin,  // [B*H*W][CINP]
    const unsigned short* __restrict__ wpk,  // [CINP/8][OCP][8]
    const float* __restrict__ bias, unsigned short* __restrict__ yout,
    int H, int W, int Cout, int OCP, int CT, int coff, int Wo, int oh) {
  __shared__ __align__(16) unsigned short smem[NF * 2048];
  const int tid = threadIdx.x;
  const int wave = tid >> 6, lane = tid & 63;
  const int l15 = lane & 15, lq = lane >> 4;
  const int tilesX = W >> 4;
  const int perB = (H >> 4) * tilesX;
  const int b = blockIdx.x / perB;
  const int r0 = blockIdx.x % perB;
  const int ty0 = (r0 / tilesX) << 4;
  const int tx0 = (r0 % tilesX) << 4;
  const int oc0 = blockIdx.y * (NF * 16);

  f32x4 acc[4][NF];
#pragma unroll
  for (int mf = 0; mf < 4; ++mf)
#pragma unroll
    for (int nf = 0; nf < NF; ++nf) acc[mf][nf] = (f32x4){0.f, 0.f, 0.f, 0.f};

  size_t rowA[4];
#pragma unroll
  for (int mf = 0; mf < 4; ++mf)
    rowA[mf] =
        ((size_t)(b * H + ty0 + wave * 4 + mf) * W + tx0 + l15) * CINP + lq * 8;
  const unsigned short* wB = wpk + ((size_t)lq * OCP + oc0 + l15) * 8;
  const int icbStr = 4 * OCP * 8;

  constexpr int NI = CINP / 32;
#pragma unroll 2
  for (int icb = 0; icb < NI; ++icb) {
    bf16x8 va[4], vb[NF];
#pragma unroll
    for (int mf = 0; mf < 4; ++mf)
      va[mf] = *(const bf16x8*)&xin[rowA[mf] + icb * 32];
#pragma unroll
    for (int nf = 0; nf < NF; ++nf)
      vb[nf] = *(const bf16x8*)&wB[icb * icbStr + nf * 128];
    __builtin_amdgcn_s_setprio(1);
#pragma unroll
    for (int mf = 0; mf < 4; ++mf)
#pragma unroll
      for (int nf = 0; nf < NF; ++nf)
        acc[mf][nf] = __builtin_amdgcn_mfma_f32_16x16x32_bf16(
            va[mf], vb[nf], acc[mf][nf], 0, 0, 0);
    __builtin_amdgcn_s_setprio(0);
  }

  // two-pass epilogue: bias+relu, per-wave LDS transpose, 16B stores
  float bsv[NF];
#pragma unroll
  for (int nf = 0; nf < NF; ++nf) {
    int oc = oc0 + nf * 16 + l15;
    bsv[nf] = (oc < Cout) ? bias[oc] : 0.f;
  }
  unsigned short* slice = smem + wave * (NF * 512);
  const int Ho = H + 2 * oh;
#pragma unroll
  for (int pass = 0; pass < 2; ++pass) {
#pragma unroll
    for (int mf = 0; mf < 4; ++mf)
#pragma unroll
      for (int h = 0; h < NF / 2; ++h) {
        const int nf = pass * (NF / 2) + h;
#pragma unroll
        for (int r = 0; r < 4; ++r)
          slice[(mf * 16 + lq * 4 + r) * (NF * 8) + h * 16 + l15] =
              f2bf(fmaxf(acc[mf][nf][r] + bsv[nf], 0.f));
      }
#pragma unroll
    for (int j = 0; j < NF; ++j) {
      int c = j * 64 + lane;
      int pxl = c / NF;
      int ocq = (c - pxl * NF) * 8;
      uint4 v = *(uint4*)&slice[pxl * (NF * 8) + ocq];
      int pxg = wave * 64 + pxl;
      int gy = ty0 + (pxg >> 4) + oh, gx = tx0 + (pxg & 15) + oh;
      *(uint4*)&yout[((size_t)(b * Ho + gy) * Wo + gx) * CT + coff + oc0 +
                     pass * (NF * 8) + ocq] = v;
    }
  }
}

// =================== 3x3 MFMA conv (halo input, dbuf LDS A, global B) ========
// F32OUT=true: store float4 direct to NCHW f32 (acc[..][r] = 4 consecutive gx).
// vb prefetch pipeline: prime PFD taps before stage-issue (keeps early vb
// waits ahead of staging in the vmcnt FIFO), prefetch tap+PFD during MFMAs.
template <int CINP, int NF, bool F32OUT>
__global__ __launch_bounds__(256, 2) void mfma_conv3(
    const unsigned short* __restrict__ xin,  // [B][H+2][W+2][CINP] halo
    const unsigned short* __restrict__ wpk,  // [9][CINP/8][OCP][8]
    const float* __restrict__ bias, void* __restrict__ yout,
    int H, int W, int Cout, int OCP, int CT, int coff, int Wo, int oh) {
  const int Hp = H + 2, Wp = W + 2;
  constexpr int ICQS = CINP / 8;
  constexpr int NI = CINP / 32;
  constexpr int PFD = (NF <= 6) ? 2 : 1;  // vb prefetch depth (reg budget)
  constexpr int NSLOT = PFD + 1;
  __shared__ __align__(16) unsigned short smem[24576];  // 2 x 1536 chunks

  const int tid = threadIdx.x;
  const int wave = tid >> 6, lane = tid & 63;
  const int l15 = lane & 15, lq = lane >> 4;
  const int tilesX = W >> 4;
  const int perB = (H >> 4) * tilesX;
  const int b = blockIdx.x / perB;
  const int r0 = blockIdx.x % perB;
  const int ty0 = (r0 / tilesX) << 4;
  const int tx0 = (r0 % tilesX) << 4;
  const int oc0 = blockIdx.y * (NF * 16);

  f32x4 acc[4][NF];
#pragma unroll
  for (int mf = 0; mf < 4; ++mf)
#pragma unroll
    for (int nf = 0; nf < NF; ++nf) acc[mf][nf] = (f32x4){0.f, 0.f, 0.f, 0.f};

  const size_t rowbase = (size_t)(b * Hp + ty0) * Wp + tx0;
  const unsigned short* gp[6];
#pragma unroll
  for (int k = 0; k < 6; ++k) {
    int e = tid + k * 256;
    int q = e / 384;
    int r = e - q * 384;
    int rc = (r < 324) ? r : 323;  // pad lanes load a harmless valid chunk
    int py = rc / 18, px = rc - py * 18;
    gp[k] = xin + (rowbase + (size_t)py * Wp + px) * CINP + q * 8;
  }
  const unsigned short* wB = wpk + ((size_t)lq * OCP + oc0 + l15) * 8;
  const int icbStr = 4 * OCP * 8;
  const int tapStr = ICQS * OCP * 8;

#pragma unroll
  for (int k = 0; k < 6; ++k)
    gload_lds16(gp[k], smem + (tid + k * 256) * 8);

  for (int icb = 0; icb < NI; ++icb) {
    const int curOff = (icb & 1) * 12288;
    __syncthreads();  // drains stage(cur); other buf free (read last iter)
    const unsigned short* wbi = wB + icb * icbStr;
    // prime vb for the first PFD taps BEFORE issuing next-icb staging, so
    // their vmcnt waits sit ahead of the stage ops in the FIFO.
    bf16x8 vbq[NSLOT][NF];
#pragma unroll
    for (int t = 0; t < PFD; ++t)
#pragma unroll
      for (int nf = 0; nf < NF; ++nf)
        vbq[t][nf] = *(const bf16x8*)&wbi[t * tapStr + nf * 128];
    if (icb + 1 < NI) {
      const int nxtOff = curOff ^ 12288;
#pragma unroll
      for (int k = 0; k < 6; ++k)
        gload_lds16(gp[k] + (icb + 1) * 32,
                    smem + nxtOff + (tid + k * 256) * 8);
    }
#pragma unroll
    for (int tap = 0; tap < 9; ++tap) {
      const int dy = tap / 3, dx = tap - dy * 3;
      if (tap + PFD < 9) {  // prefetch tap+PFD's weights during this tap
#pragma unroll
        for (int nf = 0; nf < NF; ++nf)
          vbq[(tap + PFD) % NSLOT][nf] =
              *(const bf16x8*)&wbi[(tap + PFD) * tapStr + nf * 128];
      }
      bf16x8 va[4];
#pragma unroll
      for (int mf = 0; mf < 4; ++mf)
        va[mf] = *(const bf16x8*)
            &smem[curOff +
                  (lq * 384 + (wave * 4 + mf + dy) * 18 + l15 + dx) * 8];
      __builtin_amdgcn_s_setprio(1);
#pragma unroll
      for (int mf = 0; mf < 4; ++mf)
#pragma unroll
        for (int nf = 0; nf < NF; ++nf)
          acc[mf][nf] = __builtin_amdgcn_mfma_f32_16x16x32_bf16(
              va[mf], vbq[tap % NSLOT][nf], acc[mf][nf], 0, 0, 0);
      __builtin_amdgcn_s_setprio(0);
    }
  }
  __syncthreads();

  if constexpr (F32OUT) {
    // direct NCHW f32 store: thread holds (gy=ty0+wave*4+mf, gx=tx0+lq*4+r,
    // oc=oc0+nf*16+l15); r spans 4 consecutive gx -> one float4 per (mf,nf).
    float* op = (float*)yout;
#pragma unroll
    for (int nf = 0; nf < NF; ++nf) {
      int oc = oc0 + nf * 16 + l15;
      if (oc < Cout) {
        float bv = bias[oc];
#pragma unroll
        for (int mf = 0; mf < 4; ++mf) {
          float4 v;
          v.x = fmaxf(acc[mf][nf][0] + bv, 0.f);
          v.y = fmaxf(acc[mf][nf][1] + bv, 0.f);
          v.z = fmaxf(acc[mf][nf][2] + bv, 0.f);
          v.w = fmaxf(acc[mf][nf][3] + bv, 0.f);
          *(float4*)&op[((size_t)(b * CT + coff + oc) * H + ty0 + wave * 4 +
                         mf) *
                            W +
                        tx0 + lq * 4] = v;
        }
      }
    }
  } else {
    unsigned short* yo = (unsigned short*)yout;
    float bsv[NF];
#pragma unroll
    for (int nf = 0; nf < NF; ++nf) {
      int oc = oc0 + nf * 16 + l15;
      bsv[nf] = (oc < Cout) ? bias[oc] : 0.f;
    }
    unsigned short* slice = smem + wave * (NF * 512);
    const int Ho = H + 2 * oh;
#pragma unroll
    for (int pass = 0; pass < 2; ++pass) {
#pragma unroll
      for (int mf = 0; mf < 4; ++mf)
#pragma unroll
        for (int h = 0; h < NF / 2; ++h) {
          const int nf = pass * (NF / 2) + h;
#pragma unroll
          for (int r = 0; r < 4; ++r)
            slice[(mf * 16 + lq * 4 + r) * (NF * 8) + h * 16 + l15] =
                f2bf(fmaxf(acc[mf][nf][r] + bsv[nf], 0.f));
        }
#pragma unroll
      for (int j = 0; j < NF; ++j) {
        int c = j * 64 + lane;
        int pxl = c / NF;
        int ocq = (c - pxl * NF) * 8;
        uint4 v = *(uint4*)&slice[pxl * (NF * 8) + ocq];
        int pxg = wave * 64 + pxl;
        int gy = ty0 + (pxg >> 4) + oh, gx = tx0 + (pxg & 15) + oh;
        *(uint4*)&yo[((size_t)(b * Ho + gy) * Wo + gx) * CT + coff + oc0 +
                     pass * (NF * 8) + ocq] = v;
      }
    }
  }
}

__global__ __launch_bounds__(256) void copy_flow(const float* __restrict__ flow,
                                                 float* __restrict__ out, int B,
                                                 int HW) {
  int q = HW / 4;
  int n = B * 2 * q;
  int i = blockIdx.x * blockDim.x + threadIdx.x;
  if (i < n) {
    float4 v = ((const float4*)flow)[i];
    int p = i % q;
    int t = i / q;
    int c = t % 2;
    int bb = t / 2;
    ((float4*)out)[((bb * 128 + 126 + c) * HW) / 4 + p] = v;
  }
}

extern "C" void kernel_launch(void* const* d_in, const int* in_sizes, int n_in,
                              void* d_out, int out_size, void* d_ws,
                              size_t ws_size, hipStream_t stream) {
  const float* flow = (const float*)d_in[0];
  const float* corr = (const float*)d_in[1];
  const float* wc1 = (const float*)d_in[2];
  const float* bc1 = (const float*)d_in[3];
  const float* wc2 = (const float*)d_in[4];
  const float* bc2 = (const float*)d_in[5];
  const float* wf1 = (const float*)d_in[6];
  const float* bf1 = (const float*)d_in[7];
  const float* wf2 = (const float*)d_in[8];
  const float* bf2 = (const float*)d_in[9];
  const float* wo = (const float*)d_in[10];
  const float* bo = (const float*)d_in[11];
  float* out = (float*)d_out;

  const int B = 8, H = 96, W = 128;
  const int HW = H * W;               // 12288
  const size_t NPX = (size_t)B * HW;  // 98304

  char* ws = (char*)d_ws;
  // R0: corrT [NPX][352] bf16; then cat [8][98][130][256] bf16
  unsigned short* corrT = (unsigned short*)(ws + 0);
  unsigned short* cat = (unsigned short*)(ws + 0);
  // R1: buf1 [8][98][130][256]; then fcol [NPX][128]
  unsigned short* buf1 = (unsigned short*)(ws + 69206016);
  unsigned short* fcol = (unsigned short*)(ws + 69206016);
  // R2: flo1 [8][98][130][128]
  unsigned short* flo1 = (unsigned short*)(ws + 121389056);
  // weights
  unsigned short* p1 = (unsigned short*)(ws + 147480576);   // [1][44][256][8]
  unsigned short* p2 = (unsigned short*)(ws + 147660800);   // [9][32][192][8]
  unsigned short* p3 = (unsigned short*)(ws + 148545536);   // [9][16][64][8]
  unsigned short* p4 = (unsigned short*)(ws + 148692992);   // [9][32][128][8]
  unsigned short* pf1 = (unsigned short*)(ws + 149282816);  // [16][128][8]

  // all weight repacks in one launch
  prep_w<<<dim3(512, 5), dim3(256), 0, stream>>>(wc1, wc2, wf2, wo, wf1, p1,
                                                 p2, p3, p4, pf1);
  // corr NCHW f32 -> dense NHWC bf16 (ch padded 324->352)
  nchw2nhwc_bf16<<<dim3(NPX / 64, 6), dim3(256), 0, stream>>>(corr, corrT, 324,
                                                              352, HW);
  // conv1: 1x1 352->256 (128 oc/block), corrT -> buf1 (halo write)
  mfma_gemm<352, 8><<<dim3(384, 2), dim3(256), 0, stream>>>(
      corrT, p1, bc1, buf1, H, W, 256, 256, 256, 0, 130, 1);
  // zero halos of buf1, cat, flo1 (corrT dead now; cat aliases it)
  zero_halo3<<<dim3(512, 3), dim3(256), 0, stream>>>(buf1, cat, flo1);
  // conv2: 3x3 256->192 (96 oc/block), buf1 -> cat ch 0..191
  mfma_conv3<256, 6, false><<<dim3(384, 2), dim3(256), 0, stream>>>(
      buf1, p2, bc2, (void*)cat, H, W, 192, 192, 256, 0, 130, 1);
  // im2col flow (buf1 dead; fcol aliases it)
  im2col_flow<<<dim3(NPX * 16 / 256), dim3(256), 0, stream>>>(flow, fcol, H, W);
  // convf1 as 1x1 GEMM: 128(k)->128, fcol -> flo1 (halo write)
  mfma_gemm<128, 8><<<dim3(384, 1), dim3(256), 0, stream>>>(
      fcol, pf1, bf1, flo1, H, W, 128, 128, 128, 0, 130, 1);
  // convf2: 3x3 128->64, flo1 -> cat ch 192..255
  mfma_conv3<128, 4, false><<<dim3(384, 1), dim3(256), 0, stream>>>(
      flo1, p3, bf2, (void*)cat, H, W, 64, 64, 256, 192, 130, 1);
  // conv5: 3x3 256->126, cat -> out NCHW f32 directly (ch 0..125)
  mfma_conv3<256, 8, true><<<dim3(384, 1), dim3(256), 0, stream>>>(
      cat, p4, bo, (void*)out, H, W, 126, 128, 128, 0, 128, 0);
  // flow -> out ch 126..127
  copy_flow<<<dim3(192), dim3(256), 0, stream>>>(flow, out, B, HW);
}

// Round 8
// 492.530 us; speedup vs baseline: 1.5527x; 1.0151x over previous
//
#include <hip/hip_runtime.h>

// BasicMotionEncoder (RAFT): B=8, H=96, W=128, CORR=324.
// Round 13 = R12 (499.9 us best) + the same vmcnt-FIFO register pipeline,
// now applied to mfma_gemm (conv1 <352,8>, convf1 <128,8>):
//  - explicit 2-slot va/vb double-buffer; issue icb+1's loads BEFORE the
//    MFMA cluster so current-slot waits are counted, not drained.
//  - icb loop fully unrolled (NI constexpr) -> all slot indices compile-time.
//  - Budget: vaq 32 + vbq 64 + addr ~25 arch VGPR, acc 128 AGPR -> 2 waves.
//  - mfma_conv3 byte-identical to R12 (validated: conv2 127->96us, MfmaUtil
//    28->38, no spill).

typedef __bf16 bf16x8 __attribute__((ext_vector_type(8)));
typedef float f32x4 __attribute__((ext_vector_type(4)));

__device__ __forceinline__ unsigned short f2bf(float f) {
  __bf16 h = (__bf16)f;
  return __builtin_bit_cast(unsigned short, h);
}
__device__ __forceinline__ float bf2f(unsigned short u) {
  __bf16 h = __builtin_bit_cast(__bf16, u);
  return (float)h;
}

__device__ __forceinline__ void gload_lds16(const unsigned short* g,
                                            unsigned short* l) {
  __builtin_amdgcn_global_load_lds(
      (const __attribute__((address_space(1))) unsigned int*)g,
      (__attribute__((address_space(3))) unsigned int*)l, 16, 0, 0);
}

// ---------------- prep_w: all 5 weight repacks in one launch -----------------
__global__ __launch_bounds__(256) void prep_w(
    const float* __restrict__ wc1, const float* __restrict__ wc2,
    const float* __restrict__ wf2, const float* __restrict__ wo,
    const float* __restrict__ wf1, unsigned short* __restrict__ p1,
    unsigned short* __restrict__ p2, unsigned short* __restrict__ p3,
    unsigned short* __restrict__ p4, unsigned short* __restrict__ pf1) {
  const int task = blockIdx.y;
  const int tid0 = blockIdx.x * 256 + threadIdx.x;
  if (task < 4) {
    // OIHW f32 -> [tap][icq][OCP][8] bf16
    const float* w;
    unsigned short* dst;
    int O, I, K2, ICQ, OCP;
    if (task == 0) { w = wc1; dst = p1; O = 256; I = 324; K2 = 1;  ICQ = 44; OCP = 256; }
    else if (task == 1) { w = wc2; dst = p2; O = 192; I = 256; K2 = 9; ICQ = 32; OCP = 192; }
    else if (task == 2) { w = wf2; dst = p3; O = 64;  I = 128; K2 = 9; ICQ = 16; OCP = 64; }
    else { w = wo; dst = p4; O = 126; I = 256; K2 = 9; ICQ = 32; OCP = 128; }
    int n = K2 * ICQ * OCP * 8;
    for (int s = tid0; s < n; s += gridDim.x * 256) {
      int j = s & 7;
      int r = s >> 3;
      int oc = r % OCP;
      r /= OCP;
      int icq = r % ICQ;
      int tap = r / ICQ;
      int ic = icq * 8 + j;
      float v = (oc < O && ic < I) ? w[((size_t)oc * I + ic) * K2 + tap] : 0.f;
      dst[s] = f2bf(v);
    }
  } else {
    // wf1 [128][2][7][7] -> [kq=16][128][8], k = ic*49 + dy*7 + dx
    int s = tid0;
    if (s < 16384) {
      int j = s & 7;
      int oc = (s >> 3) & 127;
      int kq = s >> 10;
      int k = kq * 8 + j;
      float v = 0.f;
      if (k < 98) {
        int ic = k / 49;
        int tap = k - ic * 49;
        v = wf1[(oc * 2 + ic) * 49 + tap];
      }
      pf1[s] = f2bf(v);
    }
  }
}

// ------------- NCHW f32 -> NHWC bf16 (zero-padded channels) ------------------
__global__ __launch_bounds__(256) void nchw2nhwc_bf16(
    const float* __restrict__ in, unsigned short* __restrict__ outp, int C,
    int CP, int HW) {
  __shared__ float sls[64][65];
  int p0 = blockIdx.x * 64;
  int c0 = blockIdx.y * 64;
  int b = p0 / HW, hw0 = p0 % HW;
  int tid = threadIdx.x;
  for (int e = tid; e < 4096; e += 256) {
    int ch = e >> 6, px = e & 63;
    float v = 0.f;
    if (c0 + ch < C) v = in[(size_t)(b * C + c0 + ch) * HW + hw0 + px];
    sls[px][ch] = v;
  }
  __syncthreads();
  for (int e = tid; e < 512; e += 256) {
    int px = e >> 3, cc = e & 7;
    if (c0 + cc * 8 < CP) {
      unsigned short pk[8];
#pragma unroll
      for (int j = 0; j < 8; ++j) pk[j] = f2bf(sls[px][cc * 8 + j]);
      *(uint4*)&outp[(size_t)(p0 + px) * CP + c0 + cc * 8] = *(uint4*)pk;
    }
  }
}

// ------------- zero the 1-px halo border of the 3 padded buffers -------------
__global__ __launch_bounds__(256) void zero_halo3(unsigned short* b0,
                                                  unsigned short* b1,
                                                  unsigned short* b2) {
  unsigned short* buf = (blockIdx.y == 0) ? b0 : (blockIdx.y == 1) ? b1 : b2;
  const int C = (blockIdx.y == 2) ? 128 : 256;
  const int cq = C >> 3;
  int n = 8 * 452 * cq;
  int i = blockIdx.x * 256 + threadIdx.x;
  if (i >= n) return;
  int c = i % cq;
  int t = i / cq;
  int bp = t % 452;
  int bb = t / 452;
  int y, x;
  if (bp < 130) { y = 0; x = bp; }
  else if (bp < 260) { y = 97; x = bp - 130; }
  else { int r = bp - 260; y = 1 + (r >> 1); x = (r & 1) ? 129 : 0; }
  *(uint4*)&buf[((size_t)(bb * 98 + y) * 130 + x) * C + c * 8] =
      make_uint4(0, 0, 0, 0);
}

// ------------- im2col of flow: [8][2][96][128] f32 -> [NPX][128] bf16 --------
__global__ __launch_bounds__(256) void im2col_flow(const float* __restrict__ f,
                                                   unsigned short* __restrict__ o,
                                                   int H, int W) {
  int s = blockIdx.x * 256 + threadIdx.x;  // over NPX*16
  int kq = s & 15;
  int px = s >> 4;
  int HW = H * W;
  int b = px / HW;
  int r = px % HW;
  int y = r / W;
  int x = r % W;
  unsigned short pk[8];
#pragma unroll
  for (int j = 0; j < 8; ++j) {
    int k = kq * 8 + j;
    float v = 0.f;
    if (k < 98) {
      int ic = k / 49;
      int t = k - ic * 49;
      int dy = t / 7, dx = t - dy * 7;
      int yy = y + dy - 3, xx = x + dx - 3;
      if (yy >= 0 && yy < H && xx >= 0 && xx < W)
        v = f[((size_t)(b * 2 + ic) * H + yy) * W + xx];
    }
    pk[j] = f2bf(v);
  }
  *(uint4*)&o[(size_t)px * 128 + kq * 8] = *(uint4*)pk;
}

// =================== 1x1 MFMA GEMM (no LDS staging, no barriers) =============
// Block: 256 px x NF*16 oc; 4 waves x (64px x NF*16oc).
// 2-slot register double-buffer: issue icb+1 loads before icb's MFMA cluster.
template <int CINP, int NF>
__global__ __launch_bounds__(256, 2) void mfma_gemm(
    const unsigned short* __restrict__ xin,  // [B*H*W][CINP]
    const unsigned short* __restrict__ wpk,  // [CINP/8][OCP][8]
    const float* __restrict__ bias, unsigned short* __restrict__ yout,
    int H, int W, int Cout, int OCP, int CT, int coff, int Wo, int oh) {
  __shared__ __align__(16) unsigned short smem[NF * 2048];
  const int tid = threadIdx.x;
  const int wave = tid >> 6, lane = tid & 63;
  const int l15 = lane & 15, lq = lane >> 4;
  const int tilesX = W >> 4;
  const int perB = (H >> 4) * tilesX;
  const int b = blockIdx.x / perB;
  const int r0 = blockIdx.x % perB;
  const int ty0 = (r0 / tilesX) << 4;
  const int tx0 = (r0 % tilesX) << 4;
  const int oc0 = blockIdx.y * (NF * 16);

  f32x4 acc[4][NF];
#pragma unroll
  for (int mf = 0; mf < 4; ++mf)
#pragma unroll
    for (int nf = 0; nf < NF; ++nf) acc[mf][nf] = (f32x4){0.f, 0.f, 0.f, 0.f};

  size_t rowA[4];
#pragma unroll
  for (int mf = 0; mf < 4; ++mf)
    rowA[mf] =
        ((size_t)(b * H + ty0 + wave * 4 + mf) * W + tx0 + l15) * CINP + lq * 8;
  const unsigned short* wB = wpk + ((size_t)lq * OCP + oc0 + l15) * 8;
  const int icbStr = 4 * OCP * 8;

  constexpr int NI = CINP / 32;
  bf16x8 vaq[2][4], vbq[2][NF];
  // prologue: icb 0 -> slot 0
#pragma unroll
  for (int mf = 0; mf < 4; ++mf)
    vaq[0][mf] = *(const bf16x8*)&xin[rowA[mf]];
#pragma unroll
  for (int nf = 0; nf < NF; ++nf)
    vbq[0][nf] = *(const bf16x8*)&wB[nf * 128];
#pragma unroll
  for (int icb = 0; icb < NI; ++icb) {
    const int cur = icb & 1, nxt = cur ^ 1;
    if (icb + 1 < NI) {  // issue next-icb loads ahead of this icb's MFMAs
#pragma unroll
      for (int mf = 0; mf < 4; ++mf)
        vaq[nxt][mf] = *(const bf16x8*)&xin[rowA[mf] + (icb + 1) * 32];
#pragma unroll
      for (int nf = 0; nf < NF; ++nf)
        vbq[nxt][nf] = *(const bf16x8*)&wB[(icb + 1) * icbStr + nf * 128];
    }
    __builtin_amdgcn_s_setprio(1);
#pragma unroll
    for (int mf = 0; mf < 4; ++mf)
#pragma unroll
      for (int nf = 0; nf < NF; ++nf)
        acc[mf][nf] = __builtin_amdgcn_mfma_f32_16x16x32_bf16(
            vaq[cur][mf], vbq[cur][nf], acc[mf][nf], 0, 0, 0);
    __builtin_amdgcn_s_setprio(0);
  }

  // two-pass epilogue: bias+relu, per-wave LDS transpose, 16B stores
  float bsv[NF];
#pragma unroll
  for (int nf = 0; nf < NF; ++nf) {
    int oc = oc0 + nf * 16 + l15;
    bsv[nf] = (oc < Cout) ? bias[oc] : 0.f;
  }
  unsigned short* slice = smem + wave * (NF * 512);
  const int Ho = H + 2 * oh;
#pragma unroll
  for (int pass = 0; pass < 2; ++pass) {
#pragma unroll
    for (int mf = 0; mf < 4; ++mf)
#pragma unroll
      for (int h = 0; h < NF / 2; ++h) {
        const int nf = pass * (NF / 2) + h;
#pragma unroll
        for (int r = 0; r < 4; ++r)
          slice[(mf * 16 + lq * 4 + r) * (NF * 8) + h * 16 + l15] =
              f2bf(fmaxf(acc[mf][nf][r] + bsv[nf], 0.f));
      }
#pragma unroll
    for (int j = 0; j < NF; ++j) {
      int c = j * 64 + lane;
      int pxl = c / NF;
      int ocq = (c - pxl * NF) * 8;
      uint4 v = *(uint4*)&slice[pxl * (NF * 8) + ocq];
      int pxg = wave * 64 + pxl;
      int gy = ty0 + (pxg >> 4) + oh, gx = tx0 + (pxg & 15) + oh;
      *(uint4*)&yout[((size_t)(b * Ho + gy) * Wo + gx) * CT + coff + oc0 +
                     pass * (NF * 8) + ocq] = v;
    }
  }
}

// =================== 3x3 MFMA conv (halo input, dbuf LDS A, global B) ========
// F32OUT=true: store float4 direct to NCHW f32 (acc[..][r] = 4 consecutive gx).
// vb prefetch pipeline: prime PFD taps before stage-issue (keeps early vb
// waits ahead of staging in the vmcnt FIFO), prefetch tap+PFD during MFMAs.
template <int CINP, int NF, bool F32OUT>
__global__ __launch_bounds__(256, 2) void mfma_conv3(
    const unsigned short* __restrict__ xin,  // [B][H+2][W+2][CINP] halo
    const unsigned short* __restrict__ wpk,  // [9][CINP/8][OCP][8]
    const float* __restrict__ bias, void* __restrict__ yout,
    int H, int W, int Cout, int OCP, int CT, int coff, int Wo, int oh) {
  const int Hp = H + 2, Wp = W + 2;
  constexpr int ICQS = CINP / 8;
  constexpr int NI = CINP / 32;
  constexpr int PFD = (NF <= 6) ? 2 : 1;  // vb prefetch depth (reg budget)
  constexpr int NSLOT = PFD + 1;
  __shared__ __align__(16) unsigned short smem[24576];  // 2 x 1536 chunks

  const int tid = threadIdx.x;
  const int wave = tid >> 6, lane = tid & 63;
  const int l15 = lane & 15, lq = lane >> 4;
  const int tilesX = W >> 4;
  const int perB = (H >> 4) * tilesX;
  const int b = blockIdx.x / perB;
  const int r0 = blockIdx.x % perB;
  const int ty0 = (r0 / tilesX) << 4;
  const int tx0 = (r0 % tilesX) << 4;
  const int oc0 = blockIdx.y * (NF * 16);

  f32x4 acc[4][NF];
#pragma unroll
  for (int mf = 0; mf < 4; ++mf)
#pragma unroll
    for (int nf = 0; nf < NF; ++nf) acc[mf][nf] = (f32x4){0.f, 0.f, 0.f, 0.f};

  const size_t rowbase = (size_t)(b * Hp + ty0) * Wp + tx0;
  const unsigned short* gp[6];
#pragma unroll
  for (int k = 0; k < 6; ++k) {
    int e = tid + k * 256;
    int q = e / 384;
    int r = e - q * 384;
    int rc = (r < 324) ? r : 323;  // pad lanes load a harmless valid chunk
    int py = rc / 18, px = rc - py * 18;
    gp[k] = xin + (rowbase + (size_t)py * Wp + px) * CINP + q * 8;
  }
  const unsigned short* wB = wpk + ((size_t)lq * OCP + oc0 + l15) * 8;
  const int icbStr = 4 * OCP * 8;
  const int tapStr = ICQS * OCP * 8;

#pragma unroll
  for (int k = 0; k < 6; ++k)
    gload_lds16(gp[k], smem + (tid + k * 256) * 8);

  for (int icb = 0; icb < NI; ++icb) {
    const int curOff = (icb & 1) * 12288;
    __syncthreads();  // drains stage(cur); other buf free (read last iter)
    const unsigned short* wbi = wB + icb * icbStr;
    // prime vb for the first PFD taps BEFORE issuing next-icb staging, so
    // their vmcnt waits sit ahead of the stage ops in the FIFO.
    bf16x8 vbq[NSLOT][NF];
#pragma unroll
    for (int t = 0; t < PFD; ++t)
#pragma unroll
      for (int nf = 0; nf < NF; ++nf)
        vbq[t][nf] = *(const bf16x8*)&wbi[t * tapStr + nf * 128];
    if (icb + 1 < NI) {
      const int nxtOff = curOff ^ 12288;
#pragma unroll
      for (int k = 0; k < 6; ++k)
        gload_lds16(gp[k] + (icb + 1) * 32,
                    smem + nxtOff + (tid + k * 256) * 8);
    }
#pragma unroll
    for (int tap = 0; tap < 9; ++tap) {
      const int dy = tap / 3, dx = tap - dy * 3;
      if (tap + PFD < 9) {  // prefetch tap+PFD's weights during this tap
#pragma unroll
        for (int nf = 0; nf < NF; ++nf)
          vbq[(tap + PFD) % NSLOT][nf] =
              *(const bf16x8*)&wbi[(tap + PFD) * tapStr + nf * 128];
      }
      bf16x8 va[4];
#pragma unroll
      for (int mf = 0; mf < 4; ++mf)
        va[mf] = *(const bf16x8*)
            &smem[curOff +
                  (lq * 384 + (wave * 4 + mf + dy) * 18 + l15 + dx) * 8];
      __builtin_amdgcn_s_setprio(1);
#pragma unroll
      for (int mf = 0; mf < 4; ++mf)
#pragma unroll
        for (int nf = 0; nf < NF; ++nf)
          acc[mf][nf] = __builtin_amdgcn_mfma_f32_16x16x32_bf16(
              va[mf], vbq[tap % NSLOT][nf], acc[mf][nf], 0, 0, 0);
      __builtin_amdgcn_s_setprio(0);
    }
  }
  __syncthreads();

  if constexpr (F32OUT) {
    // direct NCHW f32 store: thread holds (gy=ty0+wave*4+mf, gx=tx0+lq*4+r,
    // oc=oc0+nf*16+l15); r spans 4 consecutive gx -> one float4 per (mf,nf).
    float* op = (float*)yout;
#pragma unroll
    for (int nf = 0; nf < NF; ++nf) {
      int oc = oc0 + nf * 16 + l15;
      if (oc < Cout) {
        float bv = bias[oc];
#pragma unroll
        for (int mf = 0; mf < 4; ++mf) {
          float4 v;
          v.x = fmaxf(acc[mf][nf][0] + bv, 0.f);
          v.y = fmaxf(acc[mf][nf][1] + bv, 0.f);
          v.z = fmaxf(acc[mf][nf][2] + bv, 0.f);
          v.w = fmaxf(acc[mf][nf][3] + bv, 0.f);
          *(float4*)&op[((size_t)(b * CT + coff + oc) * H + ty0 + wave * 4 +
                         mf) *
                            W +
                        tx0 + lq * 4] = v;
        }
      }
    }
  } else {
    unsigned short* yo = (unsigned short*)yout;
    float bsv[NF];
#pragma unroll
    for (int nf = 0; nf < NF; ++nf) {
      int oc = oc0 + nf * 16 + l15;
      bsv[nf] = (oc < Cout) ? bias[oc] : 0.f;
    }
    unsigned short* slice = smem + wave * (NF * 512);
    const int Ho = H + 2 * oh;
#pragma unroll
    for (int pass = 0; pass < 2; ++pass) {
#pragma unroll
      for (int mf = 0; mf < 4; ++mf)
#pragma unroll
        for (int h = 0; h < NF / 2; ++h) {
          const int nf = pass * (NF / 2) + h;
#pragma unroll
          for (int r = 0; r < 4; ++r)
            slice[(mf * 16 + lq * 4 + r) * (NF * 8) + h * 16 + l15] =
                f2bf(fmaxf(acc[mf][nf][r] + bsv[nf], 0.f));
        }
#pragma unroll
      for (int j = 0; j < NF; ++j) {
        int c = j * 64 + lane;
        int pxl = c / NF;
        int ocq = (c - pxl * NF) * 8;
        uint4 v = *(uint4*)&slice[pxl * (NF * 8) + ocq];
        int pxg = wave * 64 + pxl;
        int gy = ty0 + (pxg >> 4) + oh, gx = tx0 + (pxg & 15) + oh;
        *(uint4*)&yo[((size_t)(b * Ho + gy) * Wo + gx) * CT + coff + oc0 +
                     pass * (NF * 8) + ocq] = v;
      }
    }
  }
}

__global__ __launch_bounds__(256) void copy_flow(const float* __restrict__ flow,
                                                 float* __restrict__ out, int B,
                                                 int HW) {
  int q = HW / 4;
  int n = B * 2 * q;
  int i = blockIdx.x * blockDim.x + threadIdx.x;
  if (i < n) {
    float4 v = ((const float4*)flow)[i];
    int p = i % q;
    int t = i / q;
    int c = t % 2;
    int bb = t / 2;
    ((float4*)out)[((bb * 128 + 126 + c) * HW) / 4 + p] = v;
  }
}

extern "C" void kernel_launch(void* const* d_in, const int* in_sizes, int n_in,
                              void* d_out, int out_size, void* d_ws,
                              size_t ws_size, hipStream_t stream) {
  const float* flow = (const float*)d_in[0];
  const float* corr = (const float*)d_in[1];
  const float* wc1 = (const float*)d_in[2];
  const float* bc1 = (const float*)d_in[3];
  const float* wc2 = (const float*)d_in[4];
  const float* bc2 = (const float*)d_in[5];
  const float* wf1 = (const float*)d_in[6];
  const float* bf1 = (const float*)d_in[7];
  const float* wf2 = (const float*)d_in[8];
  const float* bf2 = (const float*)d_in[9];
  const float* wo = (const float*)d_in[10];
  const float* bo = (const float*)d_in[11];
  float* out = (float*)d_out;

  const int B = 8, H = 96, W = 128;
  const int HW = H * W;               // 12288
  const size_t NPX = (size_t)B * HW;  // 98304

  char* ws = (char*)d_ws;
  // R0: corrT [NPX][352] bf16; then cat [8][98][130][256] bf16
  unsigned short* corrT = (unsigned short*)(ws + 0);
  unsigned short* cat = (unsigned short*)(ws + 0);
  // R1: buf1 [8][98][130][256]; then fcol [NPX][128]
  unsigned short* buf1 = (unsigned short*)(ws + 69206016);
  unsigned short* fcol = (unsigned short*)(ws + 69206016);
  // R2: flo1 [8][98][130][128]
  unsigned short* flo1 = (unsigned short*)(ws + 121389056);
  // weights
  unsigned short* p1 = (unsigned short*)(ws + 147480576);   // [1][44][256][8]
  unsigned short* p2 = (unsigned short*)(ws + 147660800);   // [9][32][192][8]
  unsigned short* p3 = (unsigned short*)(ws + 148545536);   // [9][16][64][8]
  unsigned short* p4 = (unsigned short*)(ws + 148692992);   // [9][32][128][8]
  unsigned short* pf1 = (unsigned short*)(ws + 149282816);  // [16][128][8]

  // all weight repacks in one launch
  prep_w<<<dim3(512, 5), dim3(256), 0, stream>>>(wc1, wc2, wf2, wo, wf1, p1,
                                                 p2, p3, p4, pf1);
  // corr NCHW f32 -> dense NHWC bf16 (ch padded 324->352)
  nchw2nhwc_bf16<<<dim3(NPX / 64, 6), dim3(256), 0, stream>>>(corr, corrT, 324,
                                                              352, HW);
  // conv1: 1x1 352->256 (128 oc/block), corrT -> buf1 (halo write)
  mfma_gemm<352, 8><<<dim3(384, 2), dim3(256), 0, stream>>>(
      corrT, p1, bc1, buf1, H, W, 256, 256, 256, 0, 130, 1);
  // zero halos of buf1, cat, flo1 (corrT dead now; cat aliases it)
  zero_halo3<<<dim3(512, 3), dim3(256), 0, stream>>>(buf1, cat, flo1);
  // conv2: 3x3 256->192 (96 oc/block), buf1 -> cat ch 0..191
  mfma_conv3<256, 6, false><<<dim3(384, 2), dim3(256), 0, stream>>>(
      buf1, p2, bc2, (void*)cat, H, W, 192, 192, 256, 0, 130, 1);
  // im2col flow (buf1 dead; fcol aliases it)
  im2col_flow<<<dim3(NPX * 16 / 256), dim3(256), 0, stream>>>(flow, fcol, H, W);
  // convf1 as 1x1 GEMM: 128(k)->128, fcol -> flo1 (halo write)
  mfma_gemm<128, 8><<<dim3(384, 1), dim3(256), 0, stream>>>(
      fcol, pf1, bf1, flo1, H, W, 128, 128, 128, 0, 130, 1);
  // convf2: 3x3 128->64, flo1 -> cat ch 192..255
  mfma_conv3<128, 4, false><<<dim3(384, 1), dim3(256), 0, stream>>>(
      flo1, p3, bf2, (void*)cat, H, W, 64, 64, 256, 192, 130, 1);
  // conv5: 3x3 256->126, cat -> out NCHW f32 directly (ch 0..125)
  mfma_conv3<256, 8, true><<<dim3(384, 1), dim3(256), 0, stream>>>(
      cat, p4, bo, (void*)out, H, W, 126, 128, 128, 0, 128, 0);
  // flow -> out ch 126..127
  copy_flow<<<dim3(192), dim3(256), 0, stream>>>(flow, out, B, HW);
}

// Round 9
// 473.544 us; speedup vs baseline: 1.6149x; 1.0401x over previous
//
#include <hip/hip_runtime.h>

// BasicMotionEncoder (RAFT): B=8, H=96, W=128, CORR=324.
// Round 14 = R13 (492.5 us best) + two independent levers:
//  - conv5 split <256,8>g(384,1) -> <256,4>g(384,2): acc 128->64 frees regs
//    for PFD=2 (the pipeline config validated on conv2: MfmaUtil 28->38).
//    Extra A-stage reads hit L3-resident cat, not HBM.
//  - launches 9 -> 7: prep_all = nchw2nhwc + 5 weight repacks + buf1/flo1
//    halo zero (all pre-conv1, disjoint writes); im2col_plus = im2col +
//    cat-halo zero (post-conv1, corrT dead) + copy_flow (out ch126-127,
//    disjoint from conv5's ch0-125).
//  - conv2/convf2/convf1/conv1 inner loops byte-identical to R13.

typedef __bf16 bf16x8 __attribute__((ext_vector_type(8)));
typedef float f32x4 __attribute__((ext_vector_type(4)));

__device__ __forceinline__ unsigned short f2bf(float f) {
  __bf16 h = (__bf16)f;
  return __builtin_bit_cast(unsigned short, h);
}
__device__ __forceinline__ float bf2f(unsigned short u) {
  __bf16 h = __builtin_bit_cast(__bf16, u);
  return (float)h;
}

__device__ __forceinline__ void gload_lds16(const unsigned short* g,
                                            unsigned short* l) {
  __builtin_amdgcn_global_load_lds(
      (const __attribute__((address_space(1))) unsigned int*)g,
      (__attribute__((address_space(3))) unsigned int*)l, 16, 0, 0);
}

// zero one 16B halo cell; i indexes [bb][border-pos][cq] of a [8][98][130][C]
__device__ __forceinline__ void halo_zero(unsigned short* buf, int C, int i) {
  int cq = C >> 3;
  int c = i % cq;
  int t = i / cq;
  int bp = t % 452;
  int bb = t / 452;
  int y, x;
  if (bp < 130) { y = 0; x = bp; }
  else if (bp < 260) { y = 97; x = bp - 130; }
  else { int r = bp - 260; y = 1 + (r >> 1); x = (r & 1) ? 129 : 0; }
  *(uint4*)&buf[((size_t)(bb * 98 + y) * 130 + x) * C + c * 8] =
      make_uint4(0, 0, 0, 0);
}

// ------- prep_all: NCHW->NHWC transpose + weight repacks + halo zeros -------
// grid (1536, 8): y<6 = corr transpose slice c0=y*64; y==6 = weight repacks
// (flat grid-stride over all 5 tables); y==7 = buf1+flo1 halo zero.
__global__ __launch_bounds__(256) void prep_all(
    const float* __restrict__ corr, unsigned short* __restrict__ corrT,
    const float* __restrict__ wc1, const float* __restrict__ wc2,
    const float* __restrict__ wf2, const float* __restrict__ wo,
    const float* __restrict__ wf1, unsigned short* __restrict__ p1,
    unsigned short* __restrict__ p2, unsigned short* __restrict__ p3,
    unsigned short* __restrict__ p4, unsigned short* __restrict__ pf1,
    unsigned short* __restrict__ buf1, unsigned short* __restrict__ flo1,
    int HW) {
  __shared__ float sls[64][65];
  const int tid = threadIdx.x;
  const int ty = blockIdx.y;
  if (ty < 6) {  // corr NCHW f32 -> NHWC bf16, ch padded 324->352
    const int C = 324, CP = 352;
    int p0 = blockIdx.x * 64;
    int c0 = ty * 64;
    int b = p0 / HW, hw0 = p0 % HW;
    for (int e = tid; e < 4096; e += 256) {
      int ch = e >> 6, px = e & 63;
      float v = 0.f;
      if (c0 + ch < C) v = corr[(size_t)(b * C + c0 + ch) * HW + hw0 + px];
      sls[px][ch] = v;
    }
    __syncthreads();
    for (int e = tid; e < 512; e += 256) {
      int px = e >> 3, cc = e & 7;
      if (c0 + cc * 8 < CP) {
        unsigned short pk[8];
#pragma unroll
        for (int j = 0; j < 8; ++j) pk[j] = f2bf(sls[px][cc * 8 + j]);
        *(uint4*)&corrT[(size_t)(p0 + px) * CP + c0 + cc * 8] = *(uint4*)pk;
      }
    }
  } else if (ty == 6) {  // weight repacks, flat index space 917504
    for (int s = blockIdx.x * 256 + tid; s < 917504; s += 1536 * 256) {
      if (s >= 901120) {  // wf1 [128][2][7][7] -> [kq=16][128][8]
        int t = s - 901120;
        int j = t & 7;
        int oc = (t >> 3) & 127;
        int kq = t >> 10;
        int k = kq * 8 + j;
        float v = 0.f;
        if (k < 98) {
          int ic = k / 49;
          int tap = k - ic * 49;
          v = wf1[(oc * 2 + ic) * 49 + tap];
        }
        pf1[t] = f2bf(v);
        continue;
      }
      const float* w;
      unsigned short* dst;
      int O, I, K2, ICQ, OCP, ls;
      if (s < 90112) { w = wc1; dst = p1; O = 256; I = 324; K2 = 1; ICQ = 44; OCP = 256; ls = s; }
      else if (s < 532480) { w = wc2; dst = p2; O = 192; I = 256; K2 = 9; ICQ = 32; OCP = 192; ls = s - 90112; }
      else if (s < 606208) { w = wf2; dst = p3; O = 64; I = 128; K2 = 9; ICQ = 16; OCP = 64; ls = s - 532480; }
      else { w = wo; dst = p4; O = 126; I = 256; K2 = 9; ICQ = 32; OCP = 128; ls = s - 606208; }
      int j = ls & 7;
      int r = ls >> 3;
      int oc = r % OCP;
      r /= OCP;
      int icq = r % ICQ;
      int tap = r / ICQ;
      int ic = icq * 8 + j;
      float v = (oc < O && ic < I) ? w[((size_t)oc * I + ic) * K2 + tap] : 0.f;
      dst[ls] = f2bf(v);
    }
  } else {  // halo zero: buf1 (C=256, 115712 cells) then flo1 (C=128, 57856)
    int i = blockIdx.x * 256 + tid;
    if (i < 115712) halo_zero(buf1, 256, i);
    else if (i < 173568) halo_zero(flo1, 128, i - 115712);
  }
}

// ------- im2col_plus: flow im2col + cat halo zero + flow->out copy ----------
// grid 6788: [0,6144) im2col; [6144,6596) cat halo; [6596,6788) copy_flow.
__global__ __launch_bounds__(256) void im2col_plus(
    const float* __restrict__ f, unsigned short* __restrict__ o,
    unsigned short* __restrict__ cat, float* __restrict__ out, int H, int W) {
  const int bx = blockIdx.x;
  const int tid = threadIdx.x;
  const int HW = H * W;
  if (bx < 6144) {
    int s = bx * 256 + tid;  // over NPX*16
    int kq = s & 15;
    int px = s >> 4;
    int b = px / HW;
    int r = px % HW;
    int y = r / W;
    int x = r % W;
    unsigned short pk[8];
#pragma unroll
    for (int j = 0; j < 8; ++j) {
      int k = kq * 8 + j;
      float v = 0.f;
      if (k < 98) {
        int ic = k / 49;
        int t = k - ic * 49;
        int dy = t / 7, dx = t - dy * 7;
        int yy = y + dy - 3, xx = x + dx - 3;
        if (yy >= 0 && yy < H && xx >= 0 && xx < W)
          v = f[((size_t)(b * 2 + ic) * H + yy) * W + xx];
      }
      pk[j] = f2bf(v);
    }
    *(uint4*)&o[(size_t)px * 128 + kq * 8] = *(uint4*)pk;
  } else if (bx < 6596) {
    int i = (bx - 6144) * 256 + tid;
    if (i < 115712) halo_zero(cat, 256, i);
  } else {
    int i = (bx - 6596) * 256 + tid;
    int q = HW / 4;
    int n = 8 * 2 * q;
    if (i < n) {
      float4 v = ((const float4*)f)[i];
      int p = i % q;
      int t = i / q;
      int c = t % 2;
      int bb = t / 2;
      ((float4*)out)[((bb * 128 + 126 + c) * HW) / 4 + p] = v;
    }
  }
}

// =================== 1x1 MFMA GEMM (no LDS staging, no barriers) =============
// Block: 256 px x NF*16 oc; 4 waves x (64px x NF*16oc).
// 2-slot register double-buffer: issue icb+1 loads before icb's MFMA cluster.
template <int CINP, int NF>
__global__ __launch_bounds__(256, 2) void mfma_gemm(
    const unsigned short* __restrict__ xin,  // [B*H*W][CINP]
    const unsigned short* __restrict__ wpk,  // [CINP/8][OCP][8]
    const float* __restrict__ bias, unsigned short* __restrict__ yout,
    int H, int W, int Cout, int OCP, int CT, int coff, int Wo, int oh) {
  __shared__ __align__(16) unsigned short smem[NF * 2048];
  const int tid = threadIdx.x;
  const int wave = tid >> 6, lane = tid & 63;
  const int l15 = lane & 15, lq = lane >> 4;
  const int tilesX = W >> 4;
  const int perB = (H >> 4) * tilesX;
  const int b = blockIdx.x / perB;
  const int r0 = blockIdx.x % perB;
  const int ty0 = (r0 / tilesX) << 4;
  const int tx0 = (r0 % tilesX) << 4;
  const int oc0 = blockIdx.y * (NF * 16);

  f32x4 acc[4][NF];
#pragma unroll
  for (int mf = 0; mf < 4; ++mf)
#pragma unroll
    for (int nf = 0; nf < NF; ++nf) acc[mf][nf] = (f32x4){0.f, 0.f, 0.f, 0.f};

  size_t rowA[4];
#pragma unroll
  for (int mf = 0; mf < 4; ++mf)
    rowA[mf] =
        ((size_t)(b * H + ty0 + wave * 4 + mf) * W + tx0 + l15) * CINP + lq * 8;
  const unsigned short* wB = wpk + ((size_t)lq * OCP + oc0 + l15) * 8;
  const int icbStr = 4 * OCP * 8;

  constexpr int NI = CINP / 32;
  bf16x8 vaq[2][4], vbq[2][NF];
  // prologue: icb 0 -> slot 0
#pragma unroll
  for (int mf = 0; mf < 4; ++mf)
    vaq[0][mf] = *(const bf16x8*)&xin[rowA[mf]];
#pragma unroll
  for (int nf = 0; nf < NF; ++nf)
    vbq[0][nf] = *(const bf16x8*)&wB[nf * 128];
#pragma unroll
  for (int icb = 0; icb < NI; ++icb) {
    const int cur = icb & 1, nxt = cur ^ 1;
    if (icb + 1 < NI) {  // issue next-icb loads ahead of this icb's MFMAs
#pragma unroll
      for (int mf = 0; mf < 4; ++mf)
        vaq[nxt][mf] = *(const bf16x8*)&xin[rowA[mf] + (icb + 1) * 32];
#pragma unroll
      for (int nf = 0; nf < NF; ++nf)
        vbq[nxt][nf] = *(const bf16x8*)&wB[(icb + 1) * icbStr + nf * 128];
    }
    __builtin_amdgcn_s_setprio(1);
#pragma unroll
    for (int mf = 0; mf < 4; ++mf)
#pragma unroll
      for (int nf = 0; nf < NF; ++nf)
        acc[mf][nf] = __builtin_amdgcn_mfma_f32_16x16x32_bf16(
            vaq[cur][mf], vbq[cur][nf], acc[mf][nf], 0, 0, 0);
    __builtin_amdgcn_s_setprio(0);
  }

  // two-pass epilogue: bias+relu, per-wave LDS transpose, 16B stores
  float bsv[NF];
#pragma unroll
  for (int nf = 0; nf < NF; ++nf) {
    int oc = oc0 + nf * 16 + l15;
    bsv[nf] = (oc < Cout) ? bias[oc] : 0.f;
  }
  unsigned short* slice = smem + wave * (NF * 512);
  const int Ho = H + 2 * oh;
#pragma unroll
  for (int pass = 0; pass < 2; ++pass) {
#pragma unroll
    for (int mf = 0; mf < 4; ++mf)
#pragma unroll
      for (int h = 0; h < NF / 2; ++h) {
        const int nf = pass * (NF / 2) + h;
#pragma unroll
        for (int r = 0; r < 4; ++r)
          slice[(mf * 16 + lq * 4 + r) * (NF * 8) + h * 16 + l15] =
              f2bf(fmaxf(acc[mf][nf][r] + bsv[nf], 0.f));
      }
#pragma unroll
    for (int j = 0; j < NF; ++j) {
      int c = j * 64 + lane;
      int pxl = c / NF;
      int ocq = (c - pxl * NF) * 8;
      uint4 v = *(uint4*)&slice[pxl * (NF * 8) + ocq];
      int pxg = wave * 64 + pxl;
      int gy = ty0 + (pxg >> 4) + oh, gx = tx0 + (pxg & 15) + oh;
      *(uint4*)&yout[((size_t)(b * Ho + gy) * Wo + gx) * CT + coff + oc0 +
                     pass * (NF * 8) + ocq] = v;
    }
  }
}

// =================== 3x3 MFMA conv (halo input, dbuf LDS A, global B) ========
// F32OUT=true: store float4 direct to NCHW f32 (acc[..][r] = 4 consecutive gx).
// vb prefetch pipeline: prime PFD taps before stage-issue (keeps early vb
// waits ahead of staging in the vmcnt FIFO), prefetch tap+PFD during MFMAs.
template <int CINP, int NF, bool F32OUT>
__global__ __launch_bounds__(256, 2) void mfma_conv3(
    const unsigned short* __restrict__ xin,  // [B][H+2][W+2][CINP] halo
    const unsigned short* __restrict__ wpk,  // [9][CINP/8][OCP][8]
    const float* __restrict__ bias, void* __restrict__ yout,
    int H, int W, int Cout, int OCP, int CT, int coff, int Wo, int oh) {
  const int Hp = H + 2, Wp = W + 2;
  constexpr int ICQS = CINP / 8;
  constexpr int NI = CINP / 32;
  constexpr int PFD = (NF <= 6) ? 2 : 1;  // vb prefetch depth (reg budget)
  constexpr int NSLOT = PFD + 1;
  __shared__ __align__(16) unsigned short smem[24576];  // 2 x 1536 chunks

  const int tid = threadIdx.x;
  const int wave = tid >> 6, lane = tid & 63;
  const int l15 = lane & 15, lq = lane >> 4;
  const int tilesX = W >> 4;
  const int perB = (H >> 4) * tilesX;
  const int b = blockIdx.x / perB;
  const int r0 = blockIdx.x % perB;
  const int ty0 = (r0 / tilesX) << 4;
  const int tx0 = (r0 % tilesX) << 4;
  const int oc0 = blockIdx.y * (NF * 16);

  f32x4 acc[4][NF];
#pragma unroll
  for (int mf = 0; mf < 4; ++mf)
#pragma unroll
    for (int nf = 0; nf < NF; ++nf) acc[mf][nf] = (f32x4){0.f, 0.f, 0.f, 0.f};

  const size_t rowbase = (size_t)(b * Hp + ty0) * Wp + tx0;
  const unsigned short* gp[6];
#pragma unroll
  for (int k = 0; k < 6; ++k) {
    int e = tid + k * 256;
    int q = e / 384;
    int r = e - q * 384;
    int rc = (r < 324) ? r : 323;  // pad lanes load a harmless valid chunk
    int py = rc / 18, px = rc - py * 18;
    gp[k] = xin + (rowbase + (size_t)py * Wp + px) * CINP + q * 8;
  }
  const unsigned short* wB = wpk + ((size_t)lq * OCP + oc0 + l15) * 8;
  const int icbStr = 4 * OCP * 8;
  const int tapStr = ICQS * OCP * 8;

#pragma unroll
  for (int k = 0; k < 6; ++k)
    gload_lds16(gp[k], smem + (tid + k * 256) * 8);

  for (int icb = 0; icb < NI; ++icb) {
    const int curOff = (icb & 1) * 12288;
    __syncthreads();  // drains stage(cur); other buf free (read last iter)
    const unsigned short* wbi = wB + icb * icbStr;
    // prime vb for the first PFD taps BEFORE issuing next-icb staging, so
    // their vmcnt waits sit ahead of the stage ops in the FIFO.
    bf16x8 vbq[NSLOT][NF];
#pragma unroll
    for (int t = 0; t < PFD; ++t)
#pragma unroll
      for (int nf = 0; nf < NF; ++nf)
        vbq[t][nf] = *(const bf16x8*)&wbi[t * tapStr + nf * 128];
    if (icb + 1 < NI) {
      const int nxtOff = curOff ^ 12288;
#pragma unroll
      for (int k = 0; k < 6; ++k)
        gload_lds16(gp[k] + (icb + 1) * 32,
                    smem + nxtOff + (tid + k * 256) * 8);
    }
#pragma unroll
    for (int tap = 0; tap < 9; ++tap) {
      const int dy = tap / 3, dx = tap - dy * 3;
      if (tap + PFD < 9) {  // prefetch tap+PFD's weights during this tap
#pragma unroll
        for (int nf = 0; nf < NF; ++nf)
          vbq[(tap + PFD) % NSLOT][nf] =
              *(const bf16x8*)&wbi[(tap + PFD) * tapStr + nf * 128];
      }
      bf16x8 va[4];
#pragma unroll
      for (int mf = 0; mf < 4; ++mf)
        va[mf] = *(const bf16x8*)
            &smem[curOff +
                  (lq * 384 + (wave * 4 + mf + dy) * 18 + l15 + dx) * 8];
      __builtin_amdgcn_s_setprio(1);
#pragma unroll
      for (int mf = 0; mf < 4; ++mf)
#pragma unroll
        for (int nf = 0; nf < NF; ++nf)
          acc[mf][nf] = __builtin_amdgcn_mfma_f32_16x16x32_bf16(
              va[mf], vbq[tap % NSLOT][nf], acc[mf][nf], 0, 0, 0);
      __builtin_amdgcn_s_setprio(0);
    }
  }
  __syncthreads();

  if constexpr (F32OUT) {
    // direct NCHW f32 store: thread holds (gy=ty0+wave*4+mf, gx=tx0+lq*4+r,
    // oc=oc0+nf*16+l15); r spans 4 consecutive gx -> one float4 per (mf,nf).
    float* op = (float*)yout;
#pragma unroll
    for (int nf = 0; nf < NF; ++nf) {
      int oc = oc0 + nf * 16 + l15;
      if (oc < Cout) {
        float bv = bias[oc];
#pragma unroll
        for (int mf = 0; mf < 4; ++mf) {
          float4 v;
          v.x = fmaxf(acc[mf][nf][0] + bv, 0.f);
          v.y = fmaxf(acc[mf][nf][1] + bv, 0.f);
          v.z = fmaxf(acc[mf][nf][2] + bv, 0.f);
          v.w = fmaxf(acc[mf][nf][3] + bv, 0.f);
          *(float4*)&op[((size_t)(b * CT + coff + oc) * H + ty0 + wave * 4 +
                         mf) *
                            W +
                        tx0 + lq * 4] = v;
        }
      }
    }
  } else {
    unsigned short* yo = (unsigned short*)yout;
    float bsv[NF];
#pragma unroll
    for (int nf = 0; nf < NF; ++nf) {
      int oc = oc0 + nf * 16 + l15;
      bsv[nf] = (oc < Cout) ? bias[oc] : 0.f;
    }
    unsigned short* slice = smem + wave * (NF * 512);
    const int Ho = H + 2 * oh;
#pragma unroll
    for (int pass = 0; pass < 2; ++pass) {
#pragma unroll
      for (int mf = 0; mf < 4; ++mf)
#pragma unroll
        for (int h = 0; h < NF / 2; ++h) {
          const int nf = pass * (NF / 2) + h;
#pragma unroll
          for (int r = 0; r < 4; ++r)
            slice[(mf * 16 + lq * 4 + r) * (NF * 8) + h * 16 + l15] =
                f2bf(fmaxf(acc[mf][nf][r] + bsv[nf], 0.f));
        }
#pragma unroll
      for (int j = 0; j < NF; ++j) {
        int c = j * 64 + lane;
        int pxl = c / NF;
        int ocq = (c - pxl * NF) * 8;
        uint4 v = *(uint4*)&slice[pxl * (NF * 8) + ocq];
        int pxg = wave * 64 + pxl;
        int gy = ty0 + (pxg >> 4) + oh, gx = tx0 + (pxg & 15) + oh;
        *(uint4*)&yo[((size_t)(b * Ho + gy) * Wo + gx) * CT + coff + oc0 +
                     pass * (NF * 8) + ocq] = v;
      }
    }
  }
}

extern "C" void kernel_launch(void* const* d_in, const int* in_sizes, int n_in,
                              void* d_out, int out_size, void* d_ws,
                              size_t ws_size, hipStream_t stream) {
  const float* flow = (const float*)d_in[0];
  const float* corr = (const float*)d_in[1];
  const float* wc1 = (const float*)d_in[2];
  const float* bc1 = (const float*)d_in[3];
  const float* wc2 = (const float*)d_in[4];
  const float* bc2 = (const float*)d_in[5];
  const float* wf1 = (const float*)d_in[6];
  const float* bf1 = (const float*)d_in[7];
  const float* wf2 = (const float*)d_in[8];
  const float* bf2 = (const float*)d_in[9];
  const float* wo = (const float*)d_in[10];
  const float* bo = (const float*)d_in[11];
  float* out = (float*)d_out;

  const int B = 8, H = 96, W = 128;
  const int HW = H * W;               // 12288
  const size_t NPX = (size_t)B * HW;  // 98304

  char* ws = (char*)d_ws;
  // R0: corrT [NPX][352] bf16; then cat [8][98][130][256] bf16
  unsigned short* corrT = (unsigned short*)(ws + 0);
  unsigned short* cat = (unsigned short*)(ws + 0);
  // R1: buf1 [8][98][130][256]; then fcol [NPX][128]
  unsigned short* buf1 = (unsigned short*)(ws + 69206016);
  unsigned short* fcol = (unsigned short*)(ws + 69206016);
  // R2: flo1 [8][98][130][128]
  unsigned short* flo1 = (unsigned short*)(ws + 121389056);
  // weights
  unsigned short* p1 = (unsigned short*)(ws + 147480576);   // [1][44][256][8]
  unsigned short* p2 = (unsigned short*)(ws + 147660800);   // [9][32][192][8]
  unsigned short* p3 = (unsigned short*)(ws + 148545536);   // [9][16][64][8]
  unsigned short* p4 = (unsigned short*)(ws + 148692992);   // [9][32][128][8]
  unsigned short* pf1 = (unsigned short*)(ws + 149282816);  // [16][128][8]

  // prep: corr transpose + all weight repacks + buf1/flo1 halo zero
  prep_all<<<dim3(NPX / 64, 8), dim3(256), 0, stream>>>(
      corr, corrT, wc1, wc2, wf2, wo, wf1, p1, p2, p3, p4, pf1, buf1, flo1,
      HW);
  // conv1: 1x1 352->256 (128 oc/block), corrT -> buf1 (halo write)
  mfma_gemm<352, 8><<<dim3(384, 2), dim3(256), 0, stream>>>(
      corrT, p1, bc1, buf1, H, W, 256, 256, 256, 0, 130, 1);
  // conv2: 3x3 256->192 (96 oc/block), buf1 -> cat ch 0..191
  mfma_conv3<256, 6, false><<<dim3(384, 2), dim3(256), 0, stream>>>(
      buf1, p2, bc2, (void*)cat, H, W, 192, 192, 256, 0, 130, 1);
  // im2col flow (buf1 dead; fcol aliases it) + cat halo zero (corrT dead)
  // + flow -> out ch 126..127 (disjoint from conv5's ch 0..125)
  im2col_plus<<<dim3(6788), dim3(256), 0, stream>>>(flow, fcol, cat, out, H,
                                                    W);
  // convf1 as 1x1 GEMM: 128(k)->128, fcol -> flo1 (halo write)
  mfma_gemm<128, 8><<<dim3(384, 1), dim3(256), 0, stream>>>(
      fcol, pf1, bf1, flo1, H, W, 128, 128, 128, 0, 130, 1);
  // convf2: 3x3 128->64, flo1 -> cat ch 192..255
  mfma_conv3<128, 4, false><<<dim3(384, 1), dim3(256), 0, stream>>>(
      flo1, p3, bf2, (void*)cat, H, W, 64, 64, 256, 192, 130, 1);
  // conv5: 3x3 256->126 split 2x64 oc (PFD=2 pipeline), cat -> out NCHW f32
  mfma_conv3<256, 4, true><<<dim3(384, 2), dim3(256), 0, stream>>>(
      cat, p4, bo, (void*)out, H, W, 126, 128, 128, 0, 128, 0);
}